// Round 1
// 973.512 us; speedup vs baseline: 1.1092x; 1.1092x over previous
//
#include <hip/hip_runtime.h>
#include <hip/hip_bf16.h>
#include <stdint.h>

// Problem constants
#define BB 2
#define NN 2048
#define DIM 4096
#define NH 32
#define NKV 8
#define HD 128

typedef __attribute__((ext_vector_type(8))) short short8;
typedef __attribute__((ext_vector_type(4))) float floatx4;
typedef __attribute__((ext_vector_type(16))) float floatx16;

__device__ __forceinline__ float bf2f(uint16_t u) {
  union { uint32_t u; float f; } c; c.u = ((uint32_t)u) << 16; return c.f;
}
__device__ __forceinline__ uint16_t f2bf(float f) {
  union { float f; uint32_t u; } c; c.f = f;
  uint32_t u = c.u;
  return (uint16_t)((u + 0x7fffu + ((u >> 16) & 1u)) >> 16);
}

// ---- async global->LDS, 16 B per lane (dest must be uniform base + lane*16)
typedef const __attribute__((address_space(1))) uint32_t* gas_t;
typedef __attribute__((address_space(3))) uint32_t* las_t;
__device__ __forceinline__ void gl2lds16(const uint16_t* g, uint16_t* l) {
  __builtin_amdgcn_global_load_lds((gas_t)(uintptr_t)g,
                                   (las_t)(uint32_t)(uintptr_t)l, 16, 0, 0);
}

// ---------------------------------------------------------------------------
// f32 -> bf16 bulk convert (4 elems/thread)
// ---------------------------------------------------------------------------
__global__ void cvt_bf16(const float* __restrict__ in, uint16_t* __restrict__ out,
                         long n4) {
  long i = (long)blockIdx.x * 256 + threadIdx.x;
  if (i >= n4) return;
  float4 v = ((const float4*)in)[i];
  uint16_t t[4] = {f2bf(v.x), f2bf(v.y), f2bf(v.z), f2bf(v.w)};
  ((uint64_t*)out)[i] = *(uint64_t*)t;
}

// ---------------------------------------------------------------------------
// GEMM core: C[m,n] = sum_k A[m,k]*B[n,k], bf16 operands, global_load_lds
// staging (m97 structure). 128x128 tile, 4 waves, 4x4 16x16x32 MFMA per wave.
// ---------------------------------------------------------------------------
template <bool CF32>
__device__ __forceinline__ void gemm_core(const uint16_t* __restrict__ A,
                                          const uint16_t* __restrict__ B,
                                          void* __restrict__ Cv,
                                          int N, int K, int m0, int n0,
                                          uint16_t* As, uint16_t* Bs) {
  const int tid = threadIdx.x;
  const int wave = tid >> 6, lane = tid & 63;
  const int quad = lane >> 4, l16 = lane & 15;
  const int wm = (wave >> 1) * 64, wn = (wave & 1) * 64;

  // staging: wave stages 32 rows of A and B; LDS dest = waveBase + lane*16B
  const int srow = wave * 32 + (lane >> 2);
  const int scol = (lane & 3) * 8;
  const uint16_t* gA = A + (size_t)(m0 + srow) * K + scol;
  const uint16_t* gB = B + (size_t)(n0 + srow) * K + scol;
  uint16_t* lA = &As[wave * 1024 + lane * 8];
  uint16_t* lB = &Bs[wave * 1024 + lane * 8];

  floatx4 acc[4][4] = {};

  for (int kb = 0; kb < K; kb += 32) {
    gl2lds16(gA + kb, lA);
    gl2lds16(gA + kb + (size_t)16 * K, lA + 16 * 32);
    gl2lds16(gB + kb, lB);
    gl2lds16(gB + kb + (size_t)16 * K, lB + 16 * 32);
    __syncthreads();

    short8 a[4], b[4];
#pragma unroll
    for (int i = 0; i < 4; ++i)
      a[i] = *(const short8*)(&As[(wm + i * 16 + l16) * 32 + quad * 8]);
#pragma unroll
    for (int j = 0; j < 4; ++j)
      b[j] = *(const short8*)(&Bs[(wn + j * 16 + l16) * 32 + quad * 8]);
#pragma unroll
    for (int i = 0; i < 4; ++i)
#pragma unroll
      for (int j = 0; j < 4; ++j)
        acc[i][j] = __builtin_amdgcn_mfma_f32_16x16x32_bf16(a[i], b[j], acc[i][j], 0, 0, 0);
    __syncthreads();
  }

#pragma unroll
  for (int i = 0; i < 4; ++i)
#pragma unroll
    for (int r = 0; r < 4; ++r) {
      int row = m0 + wm + i * 16 + quad * 4 + r;
#pragma unroll
      for (int j = 0; j < 4; ++j) {
        int col = n0 + wn + j * 16 + l16;
        if constexpr (CF32)
          ((float*)Cv)[(size_t)row * N + col] = acc[i][j][r];
        else
          ((uint16_t*)Cv)[(size_t)row * N + col] = f2bf(acc[i][j][r]);
      }
    }
}

template <bool CF32>
__global__ __launch_bounds__(256) void gemm_fast(const uint16_t* __restrict__ A,
                                                 const uint16_t* __restrict__ B,
                                                 void* __restrict__ Cv,
                                                 int N, int K) {
  __shared__ __align__(16) uint16_t As[128 * 32];
  __shared__ __align__(16) uint16_t Bs[128 * 32];
  gemm_core<CF32>(A, B, Cv, N, K, blockIdx.y * 128, blockIdx.x * 128, As, Bs);
}

// K projection (row-major [n][kvh*128+d]) and V^T projection fused.
// V^T = Wv (1024x4096) x X^T: gemm_core with A=Wv, B=X gives C[d_full][token],
// i.e. V pre-transposed so flash attention can stage V^T rows linearly.
// grid = dim3(8, 32, 2); z=0 -> K, z=1 -> V^T.
__global__ __launch_bounds__(256) void gemm_kv2(const uint16_t* __restrict__ A,
                                                const uint16_t* __restrict__ WK,
                                                const uint16_t* __restrict__ WV,
                                                uint16_t* __restrict__ KO,
                                                uint16_t* __restrict__ VTO) {
  __shared__ __align__(16) uint16_t As[128 * 32];
  __shared__ __align__(16) uint16_t Bs[128 * 32];
  if (blockIdx.z == 0)
    gemm_core<false>(A, WK, KO, 1024, DIM, blockIdx.y * 128, blockIdx.x * 128, As, Bs);
  else
    gemm_core<false>(WV, A, VTO, 4096, DIM, blockIdx.x * 128, blockIdx.y * 128, As, Bs);
}

// ---------------------------------------------------------------------------
// Fallback GEMM (f32 operands staged+converted in VALU) — R3-proven path,
// used only if workspace is too small for the bf16 pre-conversion buffers.
// ---------------------------------------------------------------------------
template <bool F32>
__device__ __forceinline__ void load8(const void* __restrict__ base, size_t off,
                                      uint16_t* __restrict__ lds) {
  if constexpr (F32) {
    const float* p = (const float*)base + off;
    float4 a = *(const float4*)p;
    float4 b = *(const float4*)(p + 4);
    uint16_t t[8];
    t[0] = f2bf(a.x); t[1] = f2bf(a.y); t[2] = f2bf(a.z); t[3] = f2bf(a.w);
    t[4] = f2bf(b.x); t[5] = f2bf(b.y); t[6] = f2bf(b.z); t[7] = f2bf(b.w);
    *(float4*)lds = *(float4*)t;
  } else {
    *(float4*)lds = *(const float4*)((const uint16_t*)base + off);
  }
}

template <bool AF32, bool BF32, bool CF32>
__global__ __launch_bounds__(256) void gemm_bt(const void* __restrict__ Av,
                                               const void* __restrict__ Bv,
                                               void* __restrict__ Cv,
                                               int M, int N, int K) {
  __shared__ __align__(16) uint16_t As[128 * 32];
  __shared__ __align__(16) uint16_t Bs[128 * 32];
  const int tid = threadIdx.x;
  const int wave = tid >> 6, lane = tid & 63;
  const int quad = lane >> 4, l16 = lane & 15;
  const int m0 = blockIdx.y * 128, n0 = blockIdx.x * 128;
  const int wm = (wave >> 1) * 64, wn = (wave & 1) * 64;

  floatx4 acc[4][4] = {};

  for (int kb = 0; kb < K; kb += 32) {
    int s = tid;
#pragma unroll
    for (int i = 0; i < 2; ++i, s += 256) {
      int row = s >> 2, cs = (s & 3) * 8;
      load8<AF32>(Av, (size_t)(m0 + row) * K + kb + cs, &As[row * 32 + cs]);
      load8<BF32>(Bv, (size_t)(n0 + row) * K + kb + cs, &Bs[row * 32 + cs]);
    }
    __syncthreads();

    short8 a[4], b[4];
#pragma unroll
    for (int i = 0; i < 4; ++i)
      a[i] = *(const short8*)(&As[(wm + i * 16 + l16) * 32 + quad * 8]);
#pragma unroll
    for (int j = 0; j < 4; ++j)
      b[j] = *(const short8*)(&Bs[(wn + j * 16 + l16) * 32 + quad * 8]);
#pragma unroll
    for (int i = 0; i < 4; ++i)
#pragma unroll
      for (int j = 0; j < 4; ++j)
        acc[i][j] = __builtin_amdgcn_mfma_f32_16x16x32_bf16(a[i], b[j], acc[i][j], 0, 0, 0);
    __syncthreads();
  }

#pragma unroll
  for (int i = 0; i < 4; ++i)
#pragma unroll
    for (int r = 0; r < 4; ++r) {
      int row = m0 + wm + i * 16 + quad * 4 + r;
#pragma unroll
      for (int j = 0; j < 4; ++j) {
        int col = n0 + wn + j * 16 + l16;
        if constexpr (CF32)
          ((float*)Cv)[(size_t)row * N + col] = acc[i][j][r];
        else
          ((uint16_t*)Cv)[(size_t)row * N + col] = f2bf(acc[i][j][r]);
      }
    }
}

// ---------------------------------------------------------------------------
// RoPE in-place on (B*N, H, 128) bf16. cos/sin f32 (N, 64). `scale` lets the
// attention softmax scale (1/sqrt(128)*log2e) be folded into Q for free.
// ---------------------------------------------------------------------------
__global__ void rope_kernel(uint16_t* __restrict__ qk,
                            const float* __restrict__ cosb,
                            const float* __restrict__ sinb, int H, int total,
                            float scale) {
  int idx = blockIdx.x * blockDim.x + threadIdx.x;
  if (idx >= total) return;
  int p = idx & 63;
  int nh = idx >> 6;
  int bn = nh / H;
  int n = bn & (NN - 1);
  size_t base = (size_t)nh * 128 + p * 2;
  uint32_t pr = *(const uint32_t*)(&qk[base]);
  float x0 = bf2f((uint16_t)(pr & 0xffff));
  float x1 = bf2f((uint16_t)(pr >> 16));
  float c = cosb[n * 64 + p];
  float s = sinb[n * 64 + p];
  float o0 = (x0 * c - x1 * s) * scale;
  float o1 = (x0 * s + x1 * c) * scale;
  *(uint32_t*)(&qk[base]) = (uint32_t)f2bf(o0) | ((uint32_t)f2bf(o1) << 16);
}

// ---------------------------------------------------------------------------
// OLD flash attention (4-wave, 16x16, P via LDS) — kept for the fallback path
// only (fallback produces row-major V).
// ---------------------------------------------------------------------------
#define KSTR 136
#define VSTR 72
#define PSTR 72

__global__ __launch_bounds__(256, 2) void flash_attn(const uint16_t* __restrict__ Q,
                                                     const uint16_t* __restrict__ K,
                                                     const uint16_t* __restrict__ V,
                                                     uint16_t* __restrict__ O) {
  __shared__ __align__(16) uint16_t Ks[64 * KSTR];
  __shared__ __align__(16) uint16_t Vt[128 * VSTR];
  __shared__ __align__(16) uint16_t Ps[4][32 * PSTR];

  const int tid = threadIdx.x;
  const int wave = tid >> 6, lane = tid & 63;
  const int quad = lane >> 4, l16 = lane & 15;
  const int b = blockIdx.z, h = blockIdx.y, kvh = h >> 2;
  const int qt = gridDim.x - 1 - blockIdx.x;
  const int qlo = qt * 128 + wave * 32;

  short8 aq[2][4];
#pragma unroll
  for (int mi = 0; mi < 2; ++mi) {
    const uint16_t* qrow = Q + (((size_t)(b * NN + qlo + mi * 16 + l16)) * NH + h) * HD;
#pragma unroll
    for (int kd = 0; kd < 4; ++kd)
      aq[mi][kd] = *(const short8*)(&qrow[kd * 32 + quad * 8]);
  }

  float mr[2][4], lr[2][4];
  floatx4 accO[2][8] = {};
#pragma unroll
  for (int mi = 0; mi < 2; ++mi)
#pragma unroll
    for (int r = 0; r < 4; ++r) { mr[mi][r] = -1e30f; lr[mi][r] = 0.f; }

  const float sc2 = 0.08838834764831845f * 1.4426950408889634f;
  const int ntiles = 2 * qt + 2;

  const int srow = tid >> 4;
  const int sl16 = tid & 15;
  const int d8 = sl16 * 8;

  for (int t = 0; t < ntiles; ++t) {
    const int kv0 = t * 64;

#pragma unroll
    for (int i = 0; i < 4; ++i) {
      int row = srow + i * 16;
      size_t gb = (((size_t)(b * NN + kv0 + row)) * NKV + kvh) * HD + d8;
      *(float4*)(&Ks[row * KSTR + d8]) = *(const float4*)(&K[gb]);
      uint16_t vv[8];
      *(float4*)vv = *(const float4*)(&V[gb]);
      int kvp = row ^ ((sl16 & 7) << 3);
#pragma unroll
      for (int j = 0; j < 8; ++j) Vt[(d8 + j) * VSTR + kvp] = vv[j];
    }
    __syncthreads();

    if (kv0 <= qlo + 31) {
      floatx4 s[2][4] = {};
#pragma unroll
      for (int jn = 0; jn < 4; ++jn)
#pragma unroll
        for (int kd = 0; kd < 4; ++kd) {
          short8 bk = *(const short8*)(&Ks[(jn * 16 + l16) * KSTR + kd * 32 + quad * 8]);
          s[0][jn] = __builtin_amdgcn_mfma_f32_16x16x32_bf16(aq[0][kd], bk, s[0][jn], 0, 0, 0);
          s[1][jn] = __builtin_amdgcn_mfma_f32_16x16x32_bf16(aq[1][kd], bk, s[1][jn], 0, 0, 0);
        }

      const bool needmask = (kv0 + 63) > qlo;
#pragma unroll
      for (int mi = 0; mi < 2; ++mi)
#pragma unroll
        for (int jn = 0; jn < 4; ++jn)
#pragma unroll
          for (int r = 0; r < 4; ++r) {
            float v = s[mi][jn][r] * sc2;
            if (needmask) {
              int qr = qlo + mi * 16 + quad * 4 + r;
              int kc = kv0 + jn * 16 + l16;
              if (kc > qr) v = -1e30f;
            }
            s[mi][jn][r] = v;
          }

#pragma unroll
      for (int mi = 0; mi < 2; ++mi)
#pragma unroll
        for (int r = 0; r < 4; ++r) {
          float mx = fmaxf(fmaxf(s[mi][0][r], s[mi][1][r]), fmaxf(s[mi][2][r], s[mi][3][r]));
#pragma unroll
          for (int off = 1; off < 16; off <<= 1)
            mx = fmaxf(mx, __shfl_xor(mx, off, 64));
          float mn = fmaxf(mr[mi][r], mx);
          float al = exp2f(mr[mi][r] - mn);
          mr[mi][r] = mn;
          float rs = 0.f;
#pragma unroll
          for (int jn = 0; jn < 4; ++jn) {
            float p = exp2f(s[mi][jn][r] - mn);
            s[mi][jn][r] = p;
            rs += p;
          }
#pragma unroll
          for (int off = 1; off < 16; off <<= 1)
            rs += __shfl_xor(rs, off, 64);
          lr[mi][r] = lr[mi][r] * al + rs;
#pragma unroll
          for (int jn = 0; jn < 4; ++jn)
            Ps[wave][(mi * 16 + quad * 4 + r) * PSTR + jn * 16 + l16] = f2bf(s[mi][jn][r]);
#pragma unroll
          for (int dt = 0; dt < 8; ++dt) accO[mi][dt][r] *= al;
        }

      short8 ap[2][2];
#pragma unroll
      for (int mi = 0; mi < 2; ++mi)
#pragma unroll
        for (int kk = 0; kk < 2; ++kk)
          ap[mi][kk] = *(const short8*)(&Ps[wave][(mi * 16 + l16) * PSTR + kk * 32 + quad * 8]);
#pragma unroll
      for (int dt = 0; dt < 8; ++dt) {
        int x = (2 * dt + (l16 >> 3)) & 7;
#pragma unroll
        for (int kk = 0; kk < 2; ++kk) {
          int kvb = (kk * 32 + quad * 8) ^ (x << 3);
          short8 bv = *(const short8*)(&Vt[(dt * 16 + l16) * VSTR + kvb]);
          accO[0][dt] = __builtin_amdgcn_mfma_f32_16x16x32_bf16(ap[0][kk], bv, accO[0][dt], 0, 0, 0);
          accO[1][dt] = __builtin_amdgcn_mfma_f32_16x16x32_bf16(ap[1][kk], bv, accO[1][dt], 0, 0, 0);
        }
      }
    }
    __syncthreads();
  }

#pragma unroll
  for (int mi = 0; mi < 2; ++mi)
#pragma unroll
    for (int r = 0; r < 4; ++r) lr[mi][r] = 1.f / lr[mi][r];
#pragma unroll
  for (int mi = 0; mi < 2; ++mi)
#pragma unroll
    for (int dt = 0; dt < 8; ++dt)
#pragma unroll
      for (int r = 0; r < 4; ++r) {
        int qr = qlo + mi * 16 + quad * 4 + r;
        size_t oidx = (((size_t)(b * NN + qr)) * NH + h) * HD + dt * 16 + l16;
        O[oidx] = f2bf(accO[mi][dt][r] * lr[mi][r]);
      }
}

// ---------------------------------------------------------------------------
// NEW flash attention: 8 waves x 32 q-rows (256-row q block), KV tile 64,
// swapped-operand 32x32x16 MFMA (S^T = mfma(K,Q): q = lane&31 -> softmax state
// is per-lane scalar, no P LDS round-trip). V is consumed pre-transposed
// (VT[d_full][token] from gemm_kv2). K/V tiles staged via global_load_lds with
// pre-swizzled global addresses (XOR (row&7)<<4), double-buffered: next tile's
// loads issued before current tile's compute (T3 2-phase). Q carries the
// softmax scale (folded in RoPE), so S is already in exp2 domain.
//   LDS[64KB]: per buf: Ks [64 kv][128 d] (swz) | Vs [128 d][64 kv] (swz)
// ---------------------------------------------------------------------------
__global__ __launch_bounds__(512, 2) void flash_attn2(const uint16_t* __restrict__ Qb,
                                                      const uint16_t* __restrict__ Kb,
                                                      const uint16_t* __restrict__ VTb,
                                                      uint16_t* __restrict__ Ob) {
  __shared__ __align__(16) uint16_t lds[32768];  // 2 x (8192 Ks + 8192 Vs)

  const int tid = threadIdx.x;
  const int wave = tid >> 6, lane = tid & 63;
  const int l31 = lane & 31, hi = lane >> 5;
  const int b = blockIdx.z, h = blockIdx.y, kvh = h >> 2;
  const int qt = gridDim.x - 1 - blockIdx.x;  // long blocks first
  const int qbase = qt * 256 + wave * 32;
  const int q_abs = qbase + l31;

  // Q fragments: B-operand rows = q (lane&31), k = d = kb*16 + hi*8 + j
  short8 qf[8];
  {
    const uint16_t* qrow = Qb + (((size_t)(b * NN + q_abs)) * NH + h) * HD;
#pragma unroll
    for (int kb = 0; kb < 8; ++kb)
      qf[kb] = *(const short8*)(qrow + kb * 16 + hi * 8);
  }

  floatx16 accO[4] = {};           // O^T: d = 32j + (reg&3)+8*(reg>>2)+4hi, q = l31
  float mrow = -1e30f, lrow = 0.f; // per-lane softmax state for q = qbase+l31

  const int ntiles = 4 * qt + 4;

  // staging constants (per-thread)
  const int krow = tid >> 4;            // K: 32 rows/pass, 16 lanes x 16B each
  const int kcol = (tid & 15) * 16;
  const int vrow = tid >> 3;            // V^T: 64 rows/pass, 8 lanes x 16B each
  const int vcol = (tid & 7) * 16;

#define STAGE(T, BUF)                                                               \
  {                                                                                 \
    const int kv0s = (T) * 64;                                                      \
    uint16_t* lb = &lds[(BUF) * 16384];                                             \
    _Pragma("unroll")                                                               \
    for (int p = 0; p < 2; ++p) {                                                   \
      int row = krow + 32 * p;                                                      \
      const char* g = (const char*)(Kb + (((size_t)(b * NN + kv0s + row)) * NKV + kvh) * HD); \
      gl2lds16((const uint16_t*)(g + (kcol ^ ((row & 7) << 4))),                    \
               &lb[tid * 8 + p * 4096]);                                            \
    }                                                                               \
    _Pragma("unroll")                                                               \
    for (int p = 0; p < 2; ++p) {                                                   \
      int d = vrow + 64 * p;                                                        \
      const char* g = (const char*)(VTb + ((size_t)(kvh * 128 + d)) * (BB * NN) +   \
                                    (size_t)b * NN + kv0s);                         \
      gl2lds16((const uint16_t*)(g + (vcol ^ ((d & 7) << 4))),                      \
               &lb[8192 + tid * 8 + p * 4096]);                                     \
    }                                                                               \
  }

  STAGE(0, 0);
  __syncthreads();

  for (int t = 0; t < ntiles; ++t) {
    const int buf = t & 1;
    if (t + 1 < ntiles) STAGE(t + 1, buf ^ 1);  // async prefetch over compute

    if (t * 64 <= qbase + 31) {  // wave-uniform: tile not fully masked
      const int kv0 = t * 64;
      const uint16_t* Ksb = &lds[buf * 16384];
      const uint16_t* Vsb = &lds[buf * 16384 + 8192];
      const int kswz = (l31 & 7) << 4;

      // S^T = mfma(K, Q): rows m = kv (A=K), cols n = q (B=Q)
      floatx16 s0 = {}, s1 = {};
      __builtin_amdgcn_s_setprio(1);
#pragma unroll
      for (int kb = 0; kb < 8; ++kb) {
        int colB = (32 * kb + 16 * hi) ^ kswz;
        short8 a0 = *(const short8*)((const char*)Ksb + l31 * 256 + colB);
        short8 a1 = *(const short8*)((const char*)Ksb + l31 * 256 + 8192 + colB);
        s0 = __builtin_amdgcn_mfma_f32_32x32x16_bf16(a0, qf[kb], s0, 0, 0, 0);
        s1 = __builtin_amdgcn_mfma_f32_32x32x16_bf16(a1, qf[kb], s1, 0, 0, 0);
      }
      __builtin_amdgcn_s_setprio(0);

      // causal mask: kv = kv0 + 32c + (r&3)+8*(r>>2)+4hi ; q = q_abs
      if (kv0 + 63 > qbase) {
#pragma unroll
        for (int r = 0; r < 16; ++r) {
          int kvl = kv0 + (r & 3) + 8 * (r >> 2) + 4 * hi;
          if (kvl > q_abs) s0[r] = -1e30f;
          if (kvl + 32 > q_abs) s1[r] = -1e30f;
        }
      }

      // per-lane row max over 32 values + exchange with lane^32
      float pm = fmaxf(s0[0], s1[0]);
#pragma unroll
      for (int r = 1; r < 16; ++r) pm = fmaxf(pm, fmaxf(s0[r], s1[r]));
      pm = fmaxf(pm, __shfl_xor(pm, 32, 64));

      // defer-max (T13): rescale only when the max grew by > 8 (exp2 domain)
      if (!__all(pm - mrow <= 8.f)) {
        float mn = fmaxf(mrow, pm);
        float al = exp2f(mrow - mn);
        mrow = mn;
        lrow *= al;
#pragma unroll
        for (int j = 0; j < 4; ++j)
#pragma unroll
          for (int r = 0; r < 16; ++r) accO[j][r] *= al;
      }

      float rs = 0.f;
#pragma unroll
      for (int r = 0; r < 16; ++r) { float p = exp2f(s0[r] - mrow); s0[r] = p; rs += p; }
#pragma unroll
      for (int r = 0; r < 16; ++r) { float p = exp2f(s1[r] - mrow); s1[r] = p; rs += p; }
      rs += __shfl_xor(rs, 32, 64);
      lrow += rs;

      // pack P to bf16 pairs; exchange halves with lane^32 to build B-fragments
      uint32_t W0[8], W1[8], X0[8], X1[8];
#pragma unroll
      for (int i = 0; i < 8; ++i) {
        W0[i] = (uint32_t)f2bf(s0[2 * i]) | ((uint32_t)f2bf(s0[2 * i + 1]) << 16);
        W1[i] = (uint32_t)f2bf(s1[2 * i]) | ((uint32_t)f2bf(s1[2 * i + 1]) << 16);
      }
#pragma unroll
      for (int i = 0; i < 8; ++i) {
        X0[i] = (uint32_t)__shfl_xor((int)W0[i], 32, 64);
        X1[i] = (uint32_t)__shfl_xor((int)W1[i], 32, 64);
      }

      // O^T += mfma(V^T, P): rows m = d (A=V^T), cols n = q (B=P)
      __builtin_amdgcn_s_setprio(1);
#pragma unroll
      for (int t16 = 0; t16 < 4; ++t16) {
        const uint32_t* Wc = (t16 < 2) ? W0 : W1;
        const uint32_t* Xc = (t16 < 2) ? X0 : X1;
        const int q4 = (t16 & 1) * 4;
        union { uint32_t u[4]; short8 v; } fr;
        fr.u[0] = hi ? Xc[q4 + 2] : Wc[q4 + 0];
        fr.u[1] = hi ? Xc[q4 + 3] : Wc[q4 + 1];
        fr.u[2] = hi ? Wc[q4 + 2] : Xc[q4 + 0];
        fr.u[3] = hi ? Wc[q4 + 3] : Xc[q4 + 1];
        short8 pb = fr.v;
        const int colB = 32 * t16 + 16 * hi;
#pragma unroll
        for (int j = 0; j < 4; ++j) {
          int row = 32 * j + l31;
          short8 av = *(const short8*)((const char*)Vsb + row * 128 + (colB ^ ((row & 7) << 4)));
          accO[j] = __builtin_amdgcn_mfma_f32_32x32x16_bf16(av, pb, accO[j], 0, 0, 0);
        }
      }
      __builtin_amdgcn_s_setprio(0);
    }
    __syncthreads();  // also drains next tile's global_load_lds (vmcnt(0))
  }

  // epilogue: normalize, transpose O^T -> O via per-wave LDS region, store
  float inv = 1.f / lrow;
  uint16_t* ow = &lds[wave * 4096];  // 8KB: [32 q][128 d], XOR swz (q&7)<<4
#pragma unroll
  for (int j = 0; j < 4; ++j)
#pragma unroll
    for (int p = 0; p < 8; ++p) {
      int dd = 32 * j + ((2 * p) & 3) + 8 * (p >> 1) + 4 * hi;
      uint32_t w = (uint32_t)f2bf(accO[j][2 * p] * inv) |
                   ((uint32_t)f2bf(accO[j][2 * p + 1] * inv) << 16);
      *(uint32_t*)((char*)ow + l31 * 256 + ((dd * 2) ^ ((l31 & 7) << 4))) = w;
    }
#pragma unroll
  for (int it = 0; it < 8; ++it) {
    int q = it * 4 + (lane >> 4);
    int colB = ((lane & 15) * 16) ^ ((q & 7) << 4);
    short8 v = *(const short8*)((const char*)ow + q * 256 + colB);
    int orow = qt * 256 + wave * 32 + q;
    *(short8*)(Ob + (((size_t)(b * NN + orow)) * NH + h) * HD + (lane & 15) * 8) = v;
  }
#undef STAGE
}

// ---------------------------------------------------------------------------
extern "C" void kernel_launch(void* const* d_in, const int* in_sizes, int n_in,
                              void* d_out, int out_size, void* d_ws, size_t ws_size,
                              hipStream_t stream) {
  const float* x    = (const float*)d_in[0];
  const float* wq   = (const float*)d_in[1];
  const float* wk   = (const float*)d_in[2];
  const float* wv   = (const float*)d_in[3];
  const float* wo   = (const float*)d_in[4];
  const float* cosb = (const float*)d_in[5];
  const float* sinb = (const float*)d_in[6];
  float* out = (float*)d_out;

  const size_t M = (size_t)BB * NN;        // 4096
  const size_t SZ_Q = M * DIM;             // 16.78M elems
  const size_t SZ_W = (size_t)DIM * DIM;   // 16.78M
  const size_t SZ_KV = M * NKV * HD;       // 4.19M
  const size_t SZ_WKV = (size_t)NKV * HD * DIM; // 4.19M

  const float ATT_SCALE = 0.08838834764831845f * 1.4426950408889634f;

  dim3 blk(256);
  const size_t need_fast =
      2 * (SZ_Q + 3 * SZ_W + 2 * SZ_WKV + 2 * SZ_KV + SZ_Q); // ~201 MB

  if (ws_size >= need_fast) {
    uint16_t* p = (uint16_t*)d_ws;
    uint16_t* xb    = p; p += SZ_Q;
    uint16_t* wqb   = p; p += SZ_W;
    uint16_t* wob   = p; p += SZ_W;
    uint16_t* wkb   = p; p += SZ_WKV;
    uint16_t* wvb   = p; p += SZ_WKV;
    uint16_t* qbuf  = p; p += SZ_Q;
    uint16_t* kbuf  = p; p += SZ_KV;
    uint16_t* vtbuf = p; p += SZ_KV;
    uint16_t* obuf  = p;

    // f32 -> bf16 conversions
    cvt_bf16<<<(int)(SZ_Q / 4 / 256), blk, 0, stream>>>(x, xb, SZ_Q / 4);
    cvt_bf16<<<(int)(SZ_W / 4 / 256), blk, 0, stream>>>(wq, wqb, SZ_W / 4);
    cvt_bf16<<<(int)(SZ_WKV / 4 / 256), blk, 0, stream>>>(wk, wkb, SZ_WKV / 4);
    cvt_bf16<<<(int)(SZ_WKV / 4 / 256), blk, 0, stream>>>(wv, wvb, SZ_WKV / 4);
    cvt_bf16<<<(int)(SZ_W / 4 / 256), blk, 0, stream>>>(wo, wob, SZ_W / 4);

    // projections: Q row-major, K row-major, V transposed (VT[d_full][token])
    gemm_fast<false><<<dim3(DIM / 128, M / 128), blk, 0, stream>>>(xb, wqb, qbuf, DIM, DIM);
    gemm_kv2<<<dim3(8, 32, 2), blk, 0, stream>>>(xb, wkb, wvb, kbuf, vtbuf);

    // RoPE (Q carries softmax scale folded in; V untouched)
    int totq = (int)(M * NH * 64);
    int totk = (int)(M * NKV * 64);
    rope_kernel<<<(totq + 255) / 256, blk, 0, stream>>>(qbuf, cosb, sinb, NH, totq, ATT_SCALE);
    rope_kernel<<<(totk + 255) / 256, blk, 0, stream>>>(kbuf, cosb, sinb, NKV, totk, 1.0f);

    // attention (8-wave, 256 q rows/block)
    flash_attn2<<<dim3(NN / 256, NH, BB), dim3(512), 0, stream>>>(qbuf, kbuf, vtbuf, obuf);

    // output projection -> f32
    gemm_fast<true><<<dim3(DIM / 128, M / 128), blk, 0, stream>>>(obuf, wob, out, DIM, DIM);
  } else {
    // fallback: R3-proven f32-staging path (needs ~84 MB)
    uint16_t* qbuf = (uint16_t*)d_ws;
    uint16_t* kbuf = qbuf + SZ_Q;
    uint16_t* vbuf = kbuf + SZ_KV;
    uint16_t* obuf = vbuf + SZ_KV;

    gemm_bt<true, true, false><<<dim3(DIM / 128, M / 128), blk, 0, stream>>>(x, wq, qbuf, M, DIM, DIM);
    gemm_bt<true, true, false><<<dim3((NKV * HD) / 128, M / 128), blk, 0, stream>>>(x, wk, kbuf, M, NKV * HD, DIM);
    gemm_bt<true, true, false><<<dim3((NKV * HD) / 128, M / 128), blk, 0, stream>>>(x, wv, vbuf, M, NKV * HD, DIM);

    int totq = (int)(M * NH * 64);
    int totk = (int)(M * NKV * 64);
    rope_kernel<<<(totq + 255) / 256, blk, 0, stream>>>(qbuf, cosb, sinb, NH, totq, 1.0f);
    rope_kernel<<<(totk + 255) / 256, blk, 0, stream>>>(kbuf, cosb, sinb, NKV, totk, 1.0f);

    flash_attn<<<dim3(NN / 128, NH, BB), blk, 0, stream>>>(qbuf, kbuf, vbuf, obuf);

    gemm_bt<false, true, true><<<dim3(DIM / 128, M / 128), blk, 0, stream>>>(obuf, wo, out, M, DIM, DIM);
  }
}

// Round 2
// 792.106 us; speedup vs baseline: 1.3632x; 1.2290x over previous
//
#include <hip/hip_runtime.h>
#include <hip/hip_bf16.h>
#include <stdint.h>

// Problem constants
#define BB 2
#define NN 2048
#define DIM 4096
#define NH 32
#define NKV 8
#define HD 128

typedef __attribute__((ext_vector_type(8))) short short8;
typedef __attribute__((ext_vector_type(4))) float floatx4;
typedef __attribute__((ext_vector_type(16))) float floatx16;

__device__ __forceinline__ float bf2f(uint16_t u) {
  union { uint32_t u; float f; } c; c.u = ((uint32_t)u) << 16; return c.f;
}
__device__ __forceinline__ uint16_t f2bf(float f) {
  union { float f; uint32_t u; } c; c.f = f;
  uint32_t u = c.u;
  return (uint16_t)((u + 0x7fffu + ((u >> 16) & 1u)) >> 16);
}

// ---- async global->LDS, 16 B per lane (dest must be uniform base + lane*16)
typedef const __attribute__((address_space(1))) uint32_t* gas_t;
typedef __attribute__((address_space(3))) uint32_t* las_t;
__device__ __forceinline__ void gl2lds16(const uint16_t* g, uint16_t* l) {
  __builtin_amdgcn_global_load_lds((gas_t)(uintptr_t)g,
                                   (las_t)(uint32_t)(uintptr_t)l, 16, 0, 0);
}

// ---------------------------------------------------------------------------
// f32 -> bf16 bulk convert (4 elems/thread)
// ---------------------------------------------------------------------------
__global__ void cvt_bf16(const float* __restrict__ in, uint16_t* __restrict__ out,
                         long n4) {
  long i = (long)blockIdx.x * 256 + threadIdx.x;
  if (i >= n4) return;
  float4 v = ((const float4*)in)[i];
  uint16_t t[4] = {f2bf(v.x), f2bf(v.y), f2bf(v.z), f2bf(v.w)};
  ((uint64_t*)out)[i] = *(uint64_t*)t;
}

// ---------------------------------------------------------------------------
// 256x256 8-phase GEMM (m201 template, plain HIP): C[m,n] = sum_k A[m,k]B[n,k]
// 8 waves (2Mx4N), BK=64, 128 KiB dbuf LDS (dynamic), per-wave 128x64 output.
// Per K-tile: 4 phases x {ds_read subtile | stage 1 unit | bar | lgkm0 |
// setprio(1) 16xMFMA setprio(0) | bar}; counted vmcnt(4) once per tile.
// Stage units (16KB: A-half or B-half) issued 2 tiles ahead:
//   p1:u(t+1,A,1) p2:u(t+1,B,1) p3:u(t+2,A,0) p4:u(t+2,B,0)
// LDS XOR-swizzle (row&7)<<4 applied on stage-source AND ds_read (rule 21).
// ---------------------------------------------------------------------------
template <bool CF32>
__global__ __launch_bounds__(512, 2) void gemm256_k(const uint16_t* __restrict__ A,
                                                    const uint16_t* __restrict__ B,
                                                    void* __restrict__ Cv,
                                                    int N, int K, int NX) {
  extern __shared__ __align__(16) uint16_t lds2[];
  const int tid = threadIdx.x;
  const int wave = tid >> 6, lane = tid & 63;
  const int quad = lane >> 4, l16 = lane & 15;
  const int wm = wave >> 2, wn = wave & 3;
  const int NT = K >> 6;
  const int cswz = (l16 & 7) << 4;

  // XCD-bijective block swizzle (m204)
  const int nwg = gridDim.x;
  const int q8 = nwg >> 3, r8 = nwg & 7, xc = blockIdx.x & 7, sq = blockIdx.x >> 3;
  const int lin = (xc < r8 ? xc * (q8 + 1) : r8 * (q8 + 1) + (xc - r8) * q8) + sq;
  const int m0 = (lin / NX) * 256, n0 = (lin % NX) * 256;

  // staging thread mapping: 64 rows x 8x16B per pass, 2 passes per unit
  const int srow = tid >> 3;
  const int scolB = ((tid & 7) * 16) ^ ((srow & 7) << 4);  // pre-swizzled source col

#define STAGEU(tt, opB_, h_)                                                        \
  {                                                                                 \
    const uint16_t* gsrc = (opB_) ? B : A;                                          \
    const int rb = (opB_) ? n0 : m0;                                                \
    char* lb = (char*)lds2 + ((tt) & 1) * 65536 + (opB_) * 32768 + (h_) * 16384;    \
    _Pragma("unroll")                                                               \
    for (int pp = 0; pp < 2; ++pp) {                                                \
      int rr = (h_) * 128 + pp * 64 + srow;                                         \
      const char* g = (const char*)(gsrc + (size_t)(rb + rr) * K + (tt) * 64) + scolB; \
      gl2lds16((const uint16_t*)g, (uint16_t*)(lb + pp * 8192 + tid * 16));         \
    }                                                                               \
  }

#define LDA8(kk_)                                                                   \
  _Pragma("unroll")                                                                 \
  for (int m_ = 0; m_ < 8; ++m_) {                                                  \
    int rA = wm * 128 + m_ * 16 + l16;                                              \
    a[m_][kk_] = *(const short8*)(bufA + rA * 128 +                                 \
                                  (((kk_) * 64 + quad * 16) ^ cswz));               \
  }
#define LDB4(kk_)                                                                   \
  _Pragma("unroll")                                                                 \
  for (int n_ = 0; n_ < 4; ++n_) {                                                  \
    int rB = wn * 64 + n_ * 16 + l16;                                               \
    b[n_][kk_] = *(const short8*)(bufB + rB * 128 +                                 \
                                  (((kk_) * 64 + quad * 16) ^ cswz));               \
  }

#define MMCLUSTER(kk_, nlo_)                                                        \
  _Pragma("unroll")                                                                 \
  for (int m_ = 0; m_ < 8; ++m_) {                                                  \
    acc[m_][nlo_] = __builtin_amdgcn_mfma_f32_16x16x32_bf16(a[m_][kk_], b[nlo_][kk_], acc[m_][nlo_], 0, 0, 0); \
    acc[m_][nlo_ + 1] = __builtin_amdgcn_mfma_f32_16x16x32_bf16(a[m_][kk_], b[(nlo_) + 1][kk_], acc[m_][(nlo_) + 1], 0, 0, 0); \
  }

#define SYNC_PRE()                                           \
  do {                                                       \
    __builtin_amdgcn_s_barrier();                            \
    asm volatile("s_waitcnt lgkmcnt(0)" ::: "memory");       \
    __builtin_amdgcn_sched_barrier(0);                       \
    __builtin_amdgcn_s_setprio(1);                           \
  } while (0)
#define SYNC_POST()                                          \
  do {                                                       \
    __builtin_amdgcn_s_setprio(0);                           \
    __builtin_amdgcn_s_barrier();                            \
  } while (0)

  short8 a[8][2], b[4][2];
  floatx4 acc[8][4] = {};

  // prologue: tile0 fully + first 2 units of tile1; counted drain to tile0
  STAGEU(0, 0, 0);
  STAGEU(0, 1, 0);
  STAGEU(0, 0, 1);
  STAGEU(0, 1, 1);
  if (NT > 1) {
    STAGEU(1, 0, 0);
    STAGEU(1, 1, 0);
    asm volatile("s_waitcnt vmcnt(4)" ::: "memory");
  } else {
    asm volatile("s_waitcnt vmcnt(0)" ::: "memory");
  }
  __builtin_amdgcn_s_barrier();

  for (int t = 0; t < NT; ++t) {
    const char* bufA = (const char*)lds2 + (t & 1) * 65536;
    const char* bufB = bufA + 32768;
    // p1
    LDA8(0);
    LDB4(0);
    if (t + 1 < NT) STAGEU(t + 1, 0, 1);
    SYNC_PRE();
    MMCLUSTER(0, 0);
    SYNC_POST();
    // p2
    LDA8(1);
    LDB4(1);
    if (t + 1 < NT) STAGEU(t + 1, 1, 1);
    SYNC_PRE();
    MMCLUSTER(0, 2);
    SYNC_POST();
    // p3 (A-half0 of current buf now fully read by all waves -> safe to overwrite)
    if (t + 2 < NT) STAGEU(t + 2, 0, 0);
    SYNC_PRE();
    MMCLUSTER(1, 0);
    SYNC_POST();
    // p4 + once-per-tile counted vmcnt (tile t+1 fully landed, t+2's 2 units in flight)
    if (t + 2 < NT) STAGEU(t + 2, 1, 0);
    __builtin_amdgcn_s_barrier();
    asm volatile("s_waitcnt lgkmcnt(0)" ::: "memory");
    __builtin_amdgcn_sched_barrier(0);
    __builtin_amdgcn_s_setprio(1);
    MMCLUSTER(1, 2);
    __builtin_amdgcn_s_setprio(0);
    if (t + 2 < NT)
      asm volatile("s_waitcnt vmcnt(4)" ::: "memory");
    else
      asm volatile("s_waitcnt vmcnt(0)" ::: "memory");
    __builtin_amdgcn_s_barrier();
  }

#pragma unroll
  for (int m_ = 0; m_ < 8; ++m_) {
#pragma unroll
    for (int r = 0; r < 4; ++r) {
      int row = m0 + wm * 128 + m_ * 16 + quad * 4 + r;
#pragma unroll
      for (int n_ = 0; n_ < 4; ++n_) {
        int col = n0 + wn * 64 + n_ * 16 + l16;
        if constexpr (CF32)
          ((float*)Cv)[(size_t)row * N + col] = acc[m_][n_][r];
        else
          ((uint16_t*)Cv)[(size_t)row * N + col] = f2bf(acc[m_][n_][r]);
      }
    }
  }
#undef STAGEU
#undef LDA8
#undef LDB4
#undef MMCLUSTER
#undef SYNC_PRE
#undef SYNC_POST
}

// ---------------------------------------------------------------------------
// GEMM core: C[m,n] = sum_k A[m,k]*B[n,k], bf16 operands, global_load_lds
// staging (m97 structure). 128x128 tile, 4 waves, 4x4 16x16x32 MFMA per wave.
// Kept for KV projection and as fallback if dynamic-LDS attribute fails.
// ---------------------------------------------------------------------------
template <bool CF32>
__device__ __forceinline__ void gemm_core(const uint16_t* __restrict__ A,
                                          const uint16_t* __restrict__ B,
                                          void* __restrict__ Cv,
                                          int N, int K, int m0, int n0,
                                          uint16_t* As, uint16_t* Bs) {
  const int tid = threadIdx.x;
  const int wave = tid >> 6, lane = tid & 63;
  const int quad = lane >> 4, l16 = lane & 15;
  const int wm = (wave >> 1) * 64, wn = (wave & 1) * 64;

  const int srow = wave * 32 + (lane >> 2);
  const int scol = (lane & 3) * 8;
  const uint16_t* gA = A + (size_t)(m0 + srow) * K + scol;
  const uint16_t* gB = B + (size_t)(n0 + srow) * K + scol;
  uint16_t* lA = &As[wave * 1024 + lane * 8];
  uint16_t* lB = &Bs[wave * 1024 + lane * 8];

  floatx4 acc[4][4] = {};

  for (int kb = 0; kb < K; kb += 32) {
    gl2lds16(gA + kb, lA);
    gl2lds16(gA + kb + (size_t)16 * K, lA + 16 * 32);
    gl2lds16(gB + kb, lB);
    gl2lds16(gB + kb + (size_t)16 * K, lB + 16 * 32);
    __syncthreads();

    short8 a[4], b[4];
#pragma unroll
    for (int i = 0; i < 4; ++i)
      a[i] = *(const short8*)(&As[(wm + i * 16 + l16) * 32 + quad * 8]);
#pragma unroll
    for (int j = 0; j < 4; ++j)
      b[j] = *(const short8*)(&Bs[(wn + j * 16 + l16) * 32 + quad * 8]);
#pragma unroll
    for (int i = 0; i < 4; ++i)
#pragma unroll
      for (int j = 0; j < 4; ++j)
        acc[i][j] = __builtin_amdgcn_mfma_f32_16x16x32_bf16(a[i], b[j], acc[i][j], 0, 0, 0);
    __syncthreads();
  }

#pragma unroll
  for (int i = 0; i < 4; ++i)
#pragma unroll
    for (int r = 0; r < 4; ++r) {
      int row = m0 + wm + i * 16 + quad * 4 + r;
#pragma unroll
      for (int j = 0; j < 4; ++j) {
        int col = n0 + wn + j * 16 + l16;
        if constexpr (CF32)
          ((float*)Cv)[(size_t)row * N + col] = acc[i][j][r];
        else
          ((uint16_t*)Cv)[(size_t)row * N + col] = f2bf(acc[i][j][r]);
      }
    }
}

template <bool CF32>
__global__ __launch_bounds__(256) void gemm_fast(const uint16_t* __restrict__ A,
                                                 const uint16_t* __restrict__ B,
                                                 void* __restrict__ Cv,
                                                 int N, int K) {
  __shared__ __align__(16) uint16_t As[128 * 32];
  __shared__ __align__(16) uint16_t Bs[128 * 32];
  gemm_core<CF32>(A, B, Cv, N, K, blockIdx.y * 128, blockIdx.x * 128, As, Bs);
}

// K projection (row-major) and V^T projection fused.
// V^T = Wv x X^T: gemm_core with A=Wv, B=X gives C[d_full][token].
// grid = dim3(8, 32, 2); z=0 -> K, z=1 -> V^T.
__global__ __launch_bounds__(256) void gemm_kv2(const uint16_t* __restrict__ A,
                                                const uint16_t* __restrict__ WK,
                                                const uint16_t* __restrict__ WV,
                                                uint16_t* __restrict__ KO,
                                                uint16_t* __restrict__ VTO) {
  __shared__ __align__(16) uint16_t As[128 * 32];
  __shared__ __align__(16) uint16_t Bs[128 * 32];
  if (blockIdx.z == 0)
    gemm_core<false>(A, WK, KO, 1024, DIM, blockIdx.y * 128, blockIdx.x * 128, As, Bs);
  else
    gemm_core<false>(WV, A, VTO, 4096, DIM, blockIdx.x * 128, blockIdx.y * 128, As, Bs);
}

// ---------------------------------------------------------------------------
// Fallback GEMM (f32 operands staged+converted in VALU) — used only if
// workspace is too small for the bf16 pre-conversion buffers.
// ---------------------------------------------------------------------------
template <bool F32>
__device__ __forceinline__ void load8(const void* __restrict__ base, size_t off,
                                      uint16_t* __restrict__ lds) {
  if constexpr (F32) {
    const float* p = (const float*)base + off;
    float4 a = *(const float4*)p;
    float4 b = *(const float4*)(p + 4);
    uint16_t t[8];
    t[0] = f2bf(a.x); t[1] = f2bf(a.y); t[2] = f2bf(a.z); t[3] = f2bf(a.w);
    t[4] = f2bf(b.x); t[5] = f2bf(b.y); t[6] = f2bf(b.z); t[7] = f2bf(b.w);
    *(float4*)lds = *(float4*)t;
  } else {
    *(float4*)lds = *(const float4*)((const uint16_t*)base + off);
  }
}

template <bool AF32, bool BF32, bool CF32>
__global__ __launch_bounds__(256) void gemm_bt(const void* __restrict__ Av,
                                               const void* __restrict__ Bv,
                                               void* __restrict__ Cv,
                                               int M, int N, int K) {
  __shared__ __align__(16) uint16_t As[128 * 32];
  __shared__ __align__(16) uint16_t Bs[128 * 32];
  const int tid = threadIdx.x;
  const int wave = tid >> 6, lane = tid & 63;
  const int quad = lane >> 4, l16 = lane & 15;
  const int m0 = blockIdx.y * 128, n0 = blockIdx.x * 128;
  const int wm = (wave >> 1) * 64, wn = (wave & 1) * 64;

  floatx4 acc[4][4] = {};

  for (int kb = 0; kb < K; kb += 32) {
    int s = tid;
#pragma unroll
    for (int i = 0; i < 2; ++i, s += 256) {
      int row = s >> 2, cs = (s & 3) * 8;
      load8<AF32>(Av, (size_t)(m0 + row) * K + kb + cs, &As[row * 32 + cs]);
      load8<BF32>(Bv, (size_t)(n0 + row) * K + kb + cs, &Bs[row * 32 + cs]);
    }
    __syncthreads();

    short8 a[4], b[4];
#pragma unroll
    for (int i = 0; i < 4; ++i)
      a[i] = *(const short8*)(&As[(wm + i * 16 + l16) * 32 + quad * 8]);
#pragma unroll
    for (int j = 0; j < 4; ++j)
      b[j] = *(const short8*)(&Bs[(wn + j * 16 + l16) * 32 + quad * 8]);
#pragma unroll
    for (int i = 0; i < 4; ++i)
#pragma unroll
      for (int j = 0; j < 4; ++j)
        acc[i][j] = __builtin_amdgcn_mfma_f32_16x16x32_bf16(a[i], b[j], acc[i][j], 0, 0, 0);
    __syncthreads();
  }

#pragma unroll
  for (int i = 0; i < 4; ++i)
#pragma unroll
    for (int r = 0; r < 4; ++r) {
      int row = m0 + wm + i * 16 + quad * 4 + r;
#pragma unroll
      for (int j = 0; j < 4; ++j) {
        int col = n0 + wn + j * 16 + l16;
        if constexpr (CF32)
          ((float*)Cv)[(size_t)row * N + col] = acc[i][j][r];
        else
          ((uint16_t*)Cv)[(size_t)row * N + col] = f2bf(acc[i][j][r]);
      }
    }
}

// ---------------------------------------------------------------------------
// RoPE in-place on (B*N, H, 128) bf16. cos/sin f32 (N, 64). `scale` lets the
// attention softmax scale (1/sqrt(128)*log2e) be folded into Q for free.
// ---------------------------------------------------------------------------
__global__ void rope_kernel(uint16_t* __restrict__ qk,
                            const float* __restrict__ cosb,
                            const float* __restrict__ sinb, int H, int total,
                            float scale) {
  int idx = blockIdx.x * blockDim.x + threadIdx.x;
  if (idx >= total) return;
  int p = idx & 63;
  int nh = idx >> 6;
  int bn = nh / H;
  int n = bn & (NN - 1);
  size_t base = (size_t)nh * 128 + p * 2;
  uint32_t pr = *(const uint32_t*)(&qk[base]);
  float x0 = bf2f((uint16_t)(pr & 0xffff));
  float x1 = bf2f((uint16_t)(pr >> 16));
  float c = cosb[n * 64 + p];
  float s = sinb[n * 64 + p];
  float o0 = (x0 * c - x1 * s) * scale;
  float o1 = (x0 * s + x1 * c) * scale;
  *(uint32_t*)(&qk[base]) = (uint32_t)f2bf(o0) | ((uint32_t)f2bf(o1) << 16);
}

// ---------------------------------------------------------------------------
// OLD flash attention (4-wave, 16x16, P via LDS) — fallback path only.
// ---------------------------------------------------------------------------
#define KSTR 136
#define VSTR 72
#define PSTR 72

__global__ __launch_bounds__(256, 2) void flash_attn(const uint16_t* __restrict__ Q,
                                                     const uint16_t* __restrict__ K,
                                                     const uint16_t* __restrict__ V,
                                                     uint16_t* __restrict__ O) {
  __shared__ __align__(16) uint16_t Ks[64 * KSTR];
  __shared__ __align__(16) uint16_t Vt[128 * VSTR];
  __shared__ __align__(16) uint16_t Ps[4][32 * PSTR];

  const int tid = threadIdx.x;
  const int wave = tid >> 6, lane = tid & 63;
  const int quad = lane >> 4, l16 = lane & 15;
  const int b = blockIdx.z, h = blockIdx.y, kvh = h >> 2;
  const int qt = gridDim.x - 1 - blockIdx.x;
  const int qlo = qt * 128 + wave * 32;

  short8 aq[2][4];
#pragma unroll
  for (int mi = 0; mi < 2; ++mi) {
    const uint16_t* qrow = Q + (((size_t)(b * NN + qlo + mi * 16 + l16)) * NH + h) * HD;
#pragma unroll
    for (int kd = 0; kd < 4; ++kd)
      aq[mi][kd] = *(const short8*)(&qrow[kd * 32 + quad * 8]);
  }

  float mr[2][4], lr[2][4];
  floatx4 accO[2][8] = {};
#pragma unroll
  for (int mi = 0; mi < 2; ++mi)
#pragma unroll
    for (int r = 0; r < 4; ++r) { mr[mi][r] = -1e30f; lr[mi][r] = 0.f; }

  const float sc2 = 0.08838834764831845f * 1.4426950408889634f;
  const int ntiles = 2 * qt + 2;

  const int srow = tid >> 4;
  const int sl16 = tid & 15;
  const int d8 = sl16 * 8;

  for (int t = 0; t < ntiles; ++t) {
    const int kv0 = t * 64;

#pragma unroll
    for (int i = 0; i < 4; ++i) {
      int row = srow + i * 16;
      size_t gb = (((size_t)(b * NN + kv0 + row)) * NKV + kvh) * HD + d8;
      *(float4*)(&Ks[row * KSTR + d8]) = *(const float4*)(&K[gb]);
      uint16_t vv[8];
      *(float4*)vv = *(const float4*)(&V[gb]);
      int kvp = row ^ ((sl16 & 7) << 3);
#pragma unroll
      for (int j = 0; j < 8; ++j) Vt[(d8 + j) * VSTR + kvp] = vv[j];
    }
    __syncthreads();

    if (kv0 <= qlo + 31) {
      floatx4 s[2][4] = {};
#pragma unroll
      for (int jn = 0; jn < 4; ++jn)
#pragma unroll
        for (int kd = 0; kd < 4; ++kd) {
          short8 bk = *(const short8*)(&Ks[(jn * 16 + l16) * KSTR + kd * 32 + quad * 8]);
          s[0][jn] = __builtin_amdgcn_mfma_f32_16x16x32_bf16(aq[0][kd], bk, s[0][jn], 0, 0, 0);
          s[1][jn] = __builtin_amdgcn_mfma_f32_16x16x32_bf16(aq[1][kd], bk, s[1][jn], 0, 0, 0);
        }

      const bool needmask = (kv0 + 63) > qlo;
#pragma unroll
      for (int mi = 0; mi < 2; ++mi)
#pragma unroll
        for (int jn = 0; jn < 4; ++jn)
#pragma unroll
          for (int r = 0; r < 4; ++r) {
            float v = s[mi][jn][r] * sc2;
            if (needmask) {
              int qr = qlo + mi * 16 + quad * 4 + r;
              int kc = kv0 + jn * 16 + l16;
              if (kc > qr) v = -1e30f;
            }
            s[mi][jn][r] = v;
          }

#pragma unroll
      for (int mi = 0; mi < 2; ++mi)
#pragma unroll
        for (int r = 0; r < 4; ++r) {
          float mx = fmaxf(fmaxf(s[mi][0][r], s[mi][1][r]), fmaxf(s[mi][2][r], s[mi][3][r]));
#pragma unroll
          for (int off = 1; off < 16; off <<= 1)
            mx = fmaxf(mx, __shfl_xor(mx, off, 64));
          float mn = fmaxf(mr[mi][r], mx);
          float al = exp2f(mr[mi][r] - mn);
          mr[mi][r] = mn;
          float rs = 0.f;
#pragma unroll
          for (int jn = 0; jn < 4; ++jn) {
            float p = exp2f(s[mi][jn][r] - mn);
            s[mi][jn][r] = p;
            rs += p;
          }
#pragma unroll
          for (int off = 1; off < 16; off <<= 1)
            rs += __shfl_xor(rs, off, 64);
          lr[mi][r] = lr[mi][r] * al + rs;
#pragma unroll
          for (int jn = 0; jn < 4; ++jn)
            Ps[wave][(mi * 16 + quad * 4 + r) * PSTR + jn * 16 + l16] = f2bf(s[mi][jn][r]);
#pragma unroll
          for (int dt = 0; dt < 8; ++dt) accO[mi][dt][r] *= al;
        }

      short8 ap[2][2];
#pragma unroll
      for (int mi = 0; mi < 2; ++mi)
#pragma unroll
        for (int kk = 0; kk < 2; ++kk)
          ap[mi][kk] = *(const short8*)(&Ps[wave][(mi * 16 + l16) * PSTR + kk * 32 + quad * 8]);
#pragma unroll
      for (int dt = 0; dt < 8; ++dt) {
        int x = (2 * dt + (l16 >> 3)) & 7;
#pragma unroll
        for (int kk = 0; kk < 2; ++kk) {
          int kvb = (kk * 32 + quad * 8) ^ (x << 3);
          short8 bv = *(const short8*)(&Vt[(dt * 16 + l16) * VSTR + kvb]);
          accO[0][dt] = __builtin_amdgcn_mfma_f32_16x16x32_bf16(ap[0][kk], bv, accO[0][dt], 0, 0, 0);
          accO[1][dt] = __builtin_amdgcn_mfma_f32_16x16x32_bf16(ap[1][kk], bv, accO[1][dt], 0, 0, 0);
        }
      }
    }
    __syncthreads();
  }

#pragma unroll
  for (int mi = 0; mi < 2; ++mi)
#pragma unroll
    for (int r = 0; r < 4; ++r) lr[mi][r] = 1.f / lr[mi][r];
#pragma unroll
  for (int mi = 0; mi < 2; ++mi)
#pragma unroll
    for (int dt = 0; dt < 8; ++dt)
#pragma unroll
      for (int r = 0; r < 4; ++r) {
        int qr = qlo + mi * 16 + quad * 4 + r;
        size_t oidx = (((size_t)(b * NN + qr)) * NH + h) * HD + dt * 16 + l16;
        O[oidx] = f2bf(accO[mi][dt][r] * lr[mi][r]);
      }
}

// ---------------------------------------------------------------------------
// NEW flash attention: 8 waves x 32 q-rows, KV tile 64, swapped-operand
// 32x32x16 MFMA, V pre-transposed, swizzled gl2lds staging, 2-phase dbuf.
// ---------------------------------------------------------------------------
__global__ __launch_bounds__(512, 2) void flash_attn2(const uint16_t* __restrict__ Qb,
                                                      const uint16_t* __restrict__ Kb,
                                                      const uint16_t* __restrict__ VTb,
                                                      uint16_t* __restrict__ Ob) {
  __shared__ __align__(16) uint16_t lds[32768];  // 2 x (8192 Ks + 8192 Vs)

  const int tid = threadIdx.x;
  const int wave = tid >> 6, lane = tid & 63;
  const int l31 = lane & 31, hi = lane >> 5;
  const int b = blockIdx.z, h = blockIdx.y, kvh = h >> 2;
  const int qt = gridDim.x - 1 - blockIdx.x;  // long blocks first
  const int qbase = qt * 256 + wave * 32;
  const int q_abs = qbase + l31;

  short8 qf[8];
  {
    const uint16_t* qrow = Qb + (((size_t)(b * NN + q_abs)) * NH + h) * HD;
#pragma unroll
    for (int kb = 0; kb < 8; ++kb)
      qf[kb] = *(const short8*)(qrow + kb * 16 + hi * 8);
  }

  floatx16 accO[4] = {};
  float mrow = -1e30f, lrow = 0.f;

  const int ntiles = 4 * qt + 4;

  const int krow = tid >> 4;
  const int kcol = (tid & 15) * 16;
  const int vrow = tid >> 3;
  const int vcol = (tid & 7) * 16;

#define STAGE(T, BUF)                                                               \
  {                                                                                 \
    const int kv0s = (T) * 64;                                                      \
    uint16_t* lb = &lds[(BUF) * 16384];                                             \
    _Pragma("unroll")                                                               \
    for (int p = 0; p < 2; ++p) {                                                   \
      int row = krow + 32 * p;                                                      \
      const char* g = (const char*)(Kb + (((size_t)(b * NN + kv0s + row)) * NKV + kvh) * HD); \
      gl2lds16((const uint16_t*)(g + (kcol ^ ((row & 7) << 4))),                    \
               &lb[tid * 8 + p * 4096]);                                            \
    }                                                                               \
    _Pragma("unroll")                                                               \
    for (int p = 0; p < 2; ++p) {                                                   \
      int d = vrow + 64 * p;                                                        \
      const char* g = (const char*)(VTb + ((size_t)(kvh * 128 + d)) * (BB * NN) +   \
                                    (size_t)b * NN + kv0s);                         \
      gl2lds16((const uint16_t*)(g + (vcol ^ ((d & 7) << 4))),                      \
               &lb[8192 + tid * 8 + p * 4096]);                                     \
    }                                                                               \
  }

  STAGE(0, 0);
  __syncthreads();

  for (int t = 0; t < ntiles; ++t) {
    const int buf = t & 1;
    if (t + 1 < ntiles) STAGE(t + 1, buf ^ 1);

    if (t * 64 <= qbase + 31) {
      const int kv0 = t * 64;
      const uint16_t* Ksb = &lds[buf * 16384];
      const uint16_t* Vsb = &lds[buf * 16384 + 8192];
      const int kswz = (l31 & 7) << 4;

      floatx16 s0 = {}, s1 = {};
      __builtin_amdgcn_s_setprio(1);
#pragma unroll
      for (int kb = 0; kb < 8; ++kb) {
        int colB = (32 * kb + 16 * hi) ^ kswz;
        short8 a0 = *(const short8*)((const char*)Ksb + l31 * 256 + colB);
        short8 a1 = *(const short8*)((const char*)Ksb + l31 * 256 + 8192 + colB);
        s0 = __builtin_amdgcn_mfma_f32_32x32x16_bf16(a0, qf[kb], s0, 0, 0, 0);
        s1 = __builtin_amdgcn_mfma_f32_32x32x16_bf16(a1, qf[kb], s1, 0, 0, 0);
      }
      __builtin_amdgcn_s_setprio(0);

      if (kv0 + 63 > qbase) {
#pragma unroll
        for (int r = 0; r < 16; ++r) {
          int kvl = kv0 + (r & 3) + 8 * (r >> 2) + 4 * hi;
          if (kvl > q_abs) s0[r] = -1e30f;
          if (kvl + 32 > q_abs) s1[r] = -1e30f;
        }
      }

      float pm = fmaxf(s0[0], s1[0]);
#pragma unroll
      for (int r = 1; r < 16; ++r) pm = fmaxf(pm, fmaxf(s0[r], s1[r]));
      pm = fmaxf(pm, __shfl_xor(pm, 32, 64));

      if (!__all(pm - mrow <= 8.f)) {
        float mn = fmaxf(mrow, pm);
        float al = exp2f(mrow - mn);
        mrow = mn;
        lrow *= al;
#pragma unroll
        for (int j = 0; j < 4; ++j)
#pragma unroll
          for (int r = 0; r < 16; ++r) accO[j][r] *= al;
      }

      float rs = 0.f;
#pragma unroll
      for (int r = 0; r < 16; ++r) { float p = exp2f(s0[r] - mrow); s0[r] = p; rs += p; }
#pragma unroll
      for (int r = 0; r < 16; ++r) { float p = exp2f(s1[r] - mrow); s1[r] = p; rs += p; }
      rs += __shfl_xor(rs, 32, 64);
      lrow += rs;

      uint32_t W0[8], W1[8], X0[8], X1[8];
#pragma unroll
      for (int i = 0; i < 8; ++i) {
        W0[i] = (uint32_t)f2bf(s0[2 * i]) | ((uint32_t)f2bf(s0[2 * i + 1]) << 16);
        W1[i] = (uint32_t)f2bf(s1[2 * i]) | ((uint32_t)f2bf(s1[2 * i + 1]) << 16);
      }
#pragma unroll
      for (int i = 0; i < 8; ++i) {
        X0[i] = (uint32_t)__shfl_xor((int)W0[i], 32, 64);
        X1[i] = (uint32_t)__shfl_xor((int)W1[i], 32, 64);
      }

      __builtin_amdgcn_s_setprio(1);
#pragma unroll
      for (int t16 = 0; t16 < 4; ++t16) {
        const uint32_t* Wc = (t16 < 2) ? W0 : W1;
        const uint32_t* Xc = (t16 < 2) ? X0 : X1;
        const int q4 = (t16 & 1) * 4;
        union { uint32_t u[4]; short8 v; } fr;
        fr.u[0] = hi ? Xc[q4 + 2] : Wc[q4 + 0];
        fr.u[1] = hi ? Xc[q4 + 3] : Wc[q4 + 1];
        fr.u[2] = hi ? Wc[q4 + 2] : Xc[q4 + 0];
        fr.u[3] = hi ? Wc[q4 + 3] : Xc[q4 + 1];
        short8 pb = fr.v;
        const int colB = 32 * t16 + 16 * hi;
#pragma unroll
        for (int j = 0; j < 4; ++j) {
          int row = 32 * j + l31;
          short8 av = *(const short8*)((const char*)Vsb + row * 128 + (colB ^ ((row & 7) << 4)));
          accO[j] = __builtin_amdgcn_mfma_f32_32x32x16_bf16(av, pb, accO[j], 0, 0, 0);
        }
      }
      __builtin_amdgcn_s_setprio(0);
    }
    __syncthreads();
  }

  float inv = 1.f / lrow;
  uint16_t* ow = &lds[wave * 4096];
#pragma unroll
  for (int j = 0; j < 4; ++j)
#pragma unroll
    for (int p = 0; p < 8; ++p) {
      int dd = 32 * j + ((2 * p) & 3) + 8 * (p >> 1) + 4 * hi;
      uint32_t w = (uint32_t)f2bf(accO[j][2 * p] * inv) |
                   ((uint32_t)f2bf(accO[j][2 * p + 1] * inv) << 16);
      *(uint32_t*)((char*)ow + l31 * 256 + ((dd * 2) ^ ((l31 & 7) << 4))) = w;
    }
#pragma unroll
  for (int it = 0; it < 8; ++it) {
    int q = it * 4 + (lane >> 4);
    int colB = ((lane & 15) * 16) ^ ((q & 7) << 4);
    short8 v = *(const short8*)((const char*)ow + q * 256 + colB);
    int orow = qt * 256 + wave * 32 + q;
    *(short8*)(Ob + (((size_t)(b * NN + orow)) * NH + h) * HD + (lane & 15) * 8) = v;
  }
#undef STAGE
}

// ---------------------------------------------------------------------------
extern "C" void kernel_launch(void* const* d_in, const int* in_sizes, int n_in,
                              void* d_out, int out_size, void* d_ws, size_t ws_size,
                              hipStream_t stream) {
  const float* x    = (const float*)d_in[0];
  const float* wq   = (const float*)d_in[1];
  const float* wk   = (const float*)d_in[2];
  const float* wv   = (const float*)d_in[3];
  const float* wo   = (const float*)d_in[4];
  const float* cosb = (const float*)d_in[5];
  const float* sinb = (const float*)d_in[6];
  float* out = (float*)d_out;

  const size_t M = (size_t)BB * NN;        // 4096
  const size_t SZ_Q = M * DIM;             // 16.78M elems
  const size_t SZ_W = (size_t)DIM * DIM;   // 16.78M
  const size_t SZ_KV = M * NKV * HD;       // 4.19M
  const size_t SZ_WKV = (size_t)NKV * HD * DIM; // 4.19M

  const float ATT_SCALE = 0.08838834764831845f * 1.4426950408889634f;

  dim3 blk(256);
  const size_t need_fast =
      2 * (SZ_Q + 3 * SZ_W + 2 * SZ_WKV + 2 * SZ_KV + SZ_Q); // ~201 MB

  // one-time: request 128 KiB dynamic LDS for the 256^2 8-phase GEMM
  static int g_dyn_ok = -1;
  if (g_dyn_ok < 0) {
    hipError_t e1 = hipFuncSetAttribute(
        reinterpret_cast<const void*>(&gemm256_k<false>),
        hipFuncAttributeMaxDynamicSharedMemorySize, 131072);
    hipError_t e2 = hipFuncSetAttribute(
        reinterpret_cast<const void*>(&gemm256_k<true>),
        hipFuncAttributeMaxDynamicSharedMemorySize, 131072);
    g_dyn_ok = (e1 == hipSuccess && e2 == hipSuccess) ? 1 : 0;
  }

  if (ws_size >= need_fast) {
    uint16_t* p = (uint16_t*)d_ws;
    uint16_t* xb    = p; p += SZ_Q;
    uint16_t* wqb   = p; p += SZ_W;
    uint16_t* wob   = p; p += SZ_W;
    uint16_t* wkb   = p; p += SZ_WKV;
    uint16_t* wvb   = p; p += SZ_WKV;
    uint16_t* qbuf  = p; p += SZ_Q;
    uint16_t* kbuf  = p; p += SZ_KV;
    uint16_t* vtbuf = p; p += SZ_KV;
    uint16_t* obuf  = p;

    // f32 -> bf16 conversions
    cvt_bf16<<<(int)(SZ_Q / 4 / 256), blk, 0, stream>>>(x, xb, SZ_Q / 4);
    cvt_bf16<<<(int)(SZ_W / 4 / 256), blk, 0, stream>>>(wq, wqb, SZ_W / 4);
    cvt_bf16<<<(int)(SZ_WKV / 4 / 256), blk, 0, stream>>>(wk, wkb, SZ_WKV / 4);
    cvt_bf16<<<(int)(SZ_WKV / 4 / 256), blk, 0, stream>>>(wv, wvb, SZ_WKV / 4);
    cvt_bf16<<<(int)(SZ_W / 4 / 256), blk, 0, stream>>>(wo, wob, SZ_W / 4);

    // Q projection
    if (g_dyn_ok)
      gemm256_k<false><<<dim3(256), dim3(512), 131072, stream>>>(xb, wqb, qbuf, DIM, DIM, 16);
    else
      gemm_fast<false><<<dim3(DIM / 128, M / 128), blk, 0, stream>>>(xb, wqb, qbuf, DIM, DIM);

    // K row-major + V transposed (VT[d_full][token])
    gemm_kv2<<<dim3(8, 32, 2), blk, 0, stream>>>(xb, wkb, wvb, kbuf, vtbuf);

    // RoPE (Q carries softmax scale folded in)
    int totq = (int)(M * NH * 64);
    int totk = (int)(M * NKV * 64);
    rope_kernel<<<(totq + 255) / 256, blk, 0, stream>>>(qbuf, cosb, sinb, NH, totq, ATT_SCALE);
    rope_kernel<<<(totk + 255) / 256, blk, 0, stream>>>(kbuf, cosb, sinb, NKV, totk, 1.0f);

    // attention (8-wave, 256 q rows/block)
    flash_attn2<<<dim3(NN / 256, NH, BB), dim3(512), 0, stream>>>(qbuf, kbuf, vtbuf, obuf);

    // output projection -> f32
    if (g_dyn_ok)
      gemm256_k<true><<<dim3(256), dim3(512), 131072, stream>>>(obuf, wob, out, DIM, DIM, 16);
    else
      gemm_fast<true><<<dim3(DIM / 128, M / 128), blk, 0, stream>>>(obuf, wob, out, DIM, DIM);
  } else {
    // fallback: f32-staging path (needs ~84 MB)
    uint16_t* qbuf = (uint16_t*)d_ws;
    uint16_t* kbuf = qbuf + SZ_Q;
    uint16_t* vbuf = kbuf + SZ_KV;
    uint16_t* obuf = vbuf + SZ_KV;

    gemm_bt<true, true, false><<<dim3(DIM / 128, M / 128), blk, 0, stream>>>(x, wq, qbuf, M, DIM, DIM);
    gemm_bt<true, true, false><<<dim3((NKV * HD) / 128, M / 128), blk, 0, stream>>>(x, wk, kbuf, M, NKV * HD, DIM);
    gemm_bt<true, true, false><<<dim3((NKV * HD) / 128, M / 128), blk, 0, stream>>>(x, wv, vbuf, M, NKV * HD, DIM);

    int totq = (int)(M * NH * 64);
    int totk = (int)(M * NKV * 64);
    rope_kernel<<<(totq + 255) / 256, blk, 0, stream>>>(qbuf, cosb, sinb, NH, totq, 1.0f);
    rope_kernel<<<(totk + 255) / 256, blk, 0, stream>>>(kbuf, cosb, sinb, NKV, totk, 1.0f);

    flash_attn<<<dim3(NN / 128, NH, BB), blk, 0, stream>>>(qbuf, kbuf, vbuf, obuf);

    gemm_bt<false, true, true><<<dim3(DIM / 128, M / 128), blk, 0, stream>>>(obuf, wo, out, M, DIM, DIM);
  }
}

// Round 3
// 764.555 us; speedup vs baseline: 1.4123x; 1.0360x over previous
//
#include <hip/hip_runtime.h>
#include <hip/hip_bf16.h>
#include <stdint.h>

// Problem constants
#define BB 2
#define NN 2048
#define DIM 4096
#define NH 32
#define NKV 8
#define HD 128

typedef __attribute__((ext_vector_type(8))) short short8;
typedef __attribute__((ext_vector_type(4))) float floatx4;
typedef __attribute__((ext_vector_type(16))) float floatx16;

__device__ __forceinline__ float bf2f(uint16_t u) {
  union { uint32_t u; float f; } c; c.u = ((uint32_t)u) << 16; return c.f;
}
__device__ __forceinline__ uint16_t f2bf(float f) {
  union { float f; uint32_t u; } c; c.f = f;
  uint32_t u = c.u;
  return (uint16_t)((u + 0x7fffu + ((u >> 16) & 1u)) >> 16);
}

// ---- async global->LDS, 16 B per lane (dest must be uniform base + lane*16)
typedef const __attribute__((address_space(1))) uint32_t* gas_t;
typedef __attribute__((address_space(3))) uint32_t* las_t;
__device__ __forceinline__ void gl2lds16(const uint16_t* g, uint16_t* l) {
  __builtin_amdgcn_global_load_lds((gas_t)(uintptr_t)g,
                                   (las_t)(uint32_t)(uintptr_t)l, 16, 0, 0);
}

// ---------------------------------------------------------------------------
// f32 -> bf16 bulk convert (4 elems/thread)
// ---------------------------------------------------------------------------
__global__ void cvt_bf16(const float* __restrict__ in, uint16_t* __restrict__ out,
                         long n4) {
  long i = (long)blockIdx.x * 256 + threadIdx.x;
  if (i >= n4) return;
  float4 v = ((const float4*)in)[i];
  uint16_t t[4] = {f2bf(v.x), f2bf(v.y), f2bf(v.z), f2bf(v.w)};
  ((uint64_t*)out)[i] = *(uint64_t*)t;
}

// ---------------------------------------------------------------------------
// 256x256 8-phase GEMM core (m201 template, plain HIP).
// C[m,n] = sum_k A[m,k]*B[n,k]. 8 waves (2Mx4N), BK=64, 128 KiB dbuf LDS.
// ---------------------------------------------------------------------------
template <bool CF32>
__device__ __forceinline__ void g256_core(const uint16_t* __restrict__ A,
                                          const uint16_t* __restrict__ B,
                                          void* __restrict__ Cv,
                                          int N, int K, int m0, int n0,
                                          uint16_t* lds2) {
  const int tid = threadIdx.x;
  const int wave = tid >> 6, lane = tid & 63;
  const int quad = lane >> 4, l16 = lane & 15;
  const int wm = wave >> 2, wn = wave & 3;
  const int NT = K >> 6;
  const int cswz = (l16 & 7) << 4;

  // staging thread mapping: 64 rows x 8x16B per pass, 2 passes per unit
  const int srow = tid >> 3;
  const int scolB = ((tid & 7) * 16) ^ ((srow & 7) << 4);  // pre-swizzled source col

#define STAGEU(tt, opB_, h_)                                                        \
  {                                                                                 \
    const uint16_t* gsrc = (opB_) ? B : A;                                          \
    const int rb = (opB_) ? n0 : m0;                                                \
    char* lb = (char*)lds2 + ((tt) & 1) * 65536 + (opB_) * 32768 + (h_) * 16384;    \
    _Pragma("unroll")                                                               \
    for (int pp = 0; pp < 2; ++pp) {                                                \
      int rr = (h_) * 128 + pp * 64 + srow;                                         \
      const char* g = (const char*)(gsrc + (size_t)(rb + rr) * K + (tt) * 64) + scolB; \
      gl2lds16((const uint16_t*)g, (uint16_t*)(lb + pp * 8192 + tid * 16));         \
    }                                                                               \
  }

#define LDA8(kk_)                                                                   \
  _Pragma("unroll")                                                                 \
  for (int m_ = 0; m_ < 8; ++m_) {                                                  \
    int rA = wm * 128 + m_ * 16 + l16;                                              \
    a[m_][kk_] = *(const short8*)(bufA + rA * 128 +                                 \
                                  (((kk_) * 64 + quad * 16) ^ cswz));               \
  }
#define LDB4(kk_)                                                                   \
  _Pragma("unroll")                                                                 \
  for (int n_ = 0; n_ < 4; ++n_) {                                                  \
    int rB = wn * 64 + n_ * 16 + l16;                                               \
    b[n_][kk_] = *(const short8*)(bufB + rB * 128 +                                 \
                                  (((kk_) * 64 + quad * 16) ^ cswz));               \
  }

#define MMCLUSTER(kk_, nlo_)                                                        \
  _Pragma("unroll")                                                                 \
  for (int m_ = 0; m_ < 8; ++m_) {                                                  \
    acc[m_][nlo_] = __builtin_amdgcn_mfma_f32_16x16x32_bf16(a[m_][kk_], b[nlo_][kk_], acc[m_][nlo_], 0, 0, 0); \
    acc[m_][nlo_ + 1] = __builtin_amdgcn_mfma_f32_16x16x32_bf16(a[m_][kk_], b[(nlo_) + 1][kk_], acc[m_][(nlo_) + 1], 0, 0, 0); \
  }

#define SYNC_PRE()                                           \
  do {                                                       \
    __builtin_amdgcn_s_barrier();                            \
    asm volatile("s_waitcnt lgkmcnt(0)" ::: "memory");       \
    __builtin_amdgcn_sched_barrier(0);                       \
    __builtin_amdgcn_s_setprio(1);                           \
  } while (0)
#define SYNC_POST()                                          \
  do {                                                       \
    __builtin_amdgcn_s_setprio(0);                           \
    __builtin_amdgcn_s_barrier();                            \
  } while (0)

  short8 a[8][2], b[4][2];
  floatx4 acc[8][4] = {};

  // prologue: tile0 fully + first 2 units of tile1; counted drain to tile0
  STAGEU(0, 0, 0);
  STAGEU(0, 1, 0);
  STAGEU(0, 0, 1);
  STAGEU(0, 1, 1);
  if (NT > 1) {
    STAGEU(1, 0, 0);
    STAGEU(1, 1, 0);
    asm volatile("s_waitcnt vmcnt(4)" ::: "memory");
  } else {
    asm volatile("s_waitcnt vmcnt(0)" ::: "memory");
  }
  __builtin_amdgcn_s_barrier();

  for (int t = 0; t < NT; ++t) {
    const char* bufA = (const char*)lds2 + (t & 1) * 65536;
    const char* bufB = bufA + 32768;
    // p1
    LDA8(0);
    LDB4(0);
    if (t + 1 < NT) STAGEU(t + 1, 0, 1);
    SYNC_PRE();
    MMCLUSTER(0, 0);
    SYNC_POST();
    // p2
    LDA8(1);
    LDB4(1);
    if (t + 1 < NT) STAGEU(t + 1, 1, 1);
    SYNC_PRE();
    MMCLUSTER(0, 2);
    SYNC_POST();
    // p3
    if (t + 2 < NT) STAGEU(t + 2, 0, 0);
    SYNC_PRE();
    MMCLUSTER(1, 0);
    SYNC_POST();
    // p4 + once-per-tile counted vmcnt
    if (t + 2 < NT) STAGEU(t + 2, 1, 0);
    __builtin_amdgcn_s_barrier();
    asm volatile("s_waitcnt lgkmcnt(0)" ::: "memory");
    __builtin_amdgcn_sched_barrier(0);
    __builtin_amdgcn_s_setprio(1);
    MMCLUSTER(1, 2);
    __builtin_amdgcn_s_setprio(0);
    if (t + 2 < NT)
      asm volatile("s_waitcnt vmcnt(4)" ::: "memory");
    else
      asm volatile("s_waitcnt vmcnt(0)" ::: "memory");
    __builtin_amdgcn_s_barrier();
  }

#pragma unroll
  for (int m_ = 0; m_ < 8; ++m_) {
#pragma unroll
    for (int r = 0; r < 4; ++r) {
      int row = m0 + wm * 128 + m_ * 16 + quad * 4 + r;
#pragma unroll
      for (int n_ = 0; n_ < 4; ++n_) {
        int col = n0 + wn * 64 + n_ * 16 + l16;
        if constexpr (CF32)
          ((float*)Cv)[(size_t)row * N + col] = acc[m_][n_][r];
        else
          ((uint16_t*)Cv)[(size_t)row * N + col] = f2bf(acc[m_][n_][r]);
      }
    }
  }
#undef STAGEU
#undef LDA8
#undef LDB4
#undef MMCLUSTER
#undef SYNC_PRE
#undef SYNC_POST
}

template <bool CF32>
__global__ __launch_bounds__(512, 2) void gemm256_k(const uint16_t* __restrict__ A,
                                                    const uint16_t* __restrict__ B,
                                                    void* __restrict__ Cv,
                                                    int N, int K, int NX) {
  extern __shared__ __align__(16) uint16_t lds2[];
  // XCD-bijective block swizzle (m204)
  const int nwg = gridDim.x;
  const int q8 = nwg >> 3, r8 = nwg & 7, xc = blockIdx.x & 7, sq = blockIdx.x >> 3;
  const int lin = (xc < r8 ? xc * (q8 + 1) : r8 * (q8 + 1) + (xc - r8) * q8) + sq;
  const int m0 = (lin / NX) * 256, n0 = (lin % NX) * 256;
  g256_core<CF32>(A, B, Cv, N, K, m0, n0, lds2);
}

// K projection (C[tok][dcol], 4096x1024) + V^T projection (C[d][tok],
// 1024x4096) in one 128-block launch of the 256^2 core.
__global__ __launch_bounds__(512, 2) void gemm_kv256(const uint16_t* __restrict__ xb,
                                                     const uint16_t* __restrict__ wkb,
                                                     const uint16_t* __restrict__ wvb,
                                                     uint16_t* __restrict__ kbuf,
                                                     uint16_t* __restrict__ vtbuf) {
  extern __shared__ __align__(16) uint16_t lds2[];
  const int id = blockIdx.x;
  if (id < 64) {
    const int mt = id >> 2, nt = id & 3;
    g256_core<false>(xb, wkb, kbuf, NKV * HD, DIM, mt * 256, nt * 256, lds2);
  } else {
    const int i2 = id - 64;
    const int mt = i2 & 3, nt = i2 >> 2;
    g256_core<false>(wvb, xb, vtbuf, BB * NN, DIM, mt * 256, nt * 256, lds2);
  }
}

// ---------------------------------------------------------------------------
// 128x128 GEMM (m97 structure) — fallback if dynamic-LDS attribute fails.
// ---------------------------------------------------------------------------
template <bool CF32>
__device__ __forceinline__ void gemm_core(const uint16_t* __restrict__ A,
                                          const uint16_t* __restrict__ B,
                                          void* __restrict__ Cv,
                                          int N, int K, int m0, int n0,
                                          uint16_t* As, uint16_t* Bs) {
  const int tid = threadIdx.x;
  const int wave = tid >> 6, lane = tid & 63;
  const int quad = lane >> 4, l16 = lane & 15;
  const int wm = (wave >> 1) * 64, wn = (wave & 1) * 64;

  const int srow = wave * 32 + (lane >> 2);
  const int scol = (lane & 3) * 8;
  const uint16_t* gA = A + (size_t)(m0 + srow) * K + scol;
  const uint16_t* gB = B + (size_t)(n0 + srow) * K + scol;
  uint16_t* lA = &As[wave * 1024 + lane * 8];
  uint16_t* lB = &Bs[wave * 1024 + lane * 8];

  floatx4 acc[4][4] = {};

  for (int kb = 0; kb < K; kb += 32) {
    gl2lds16(gA + kb, lA);
    gl2lds16(gA + kb + (size_t)16 * K, lA + 16 * 32);
    gl2lds16(gB + kb, lB);
    gl2lds16(gB + kb + (size_t)16 * K, lB + 16 * 32);
    __syncthreads();

    short8 a[4], b[4];
#pragma unroll
    for (int i = 0; i < 4; ++i)
      a[i] = *(const short8*)(&As[(wm + i * 16 + l16) * 32 + quad * 8]);
#pragma unroll
    for (int j = 0; j < 4; ++j)
      b[j] = *(const short8*)(&Bs[(wn + j * 16 + l16) * 32 + quad * 8]);
#pragma unroll
    for (int i = 0; i < 4; ++i)
#pragma unroll
      for (int j = 0; j < 4; ++j)
        acc[i][j] = __builtin_amdgcn_mfma_f32_16x16x32_bf16(a[i], b[j], acc[i][j], 0, 0, 0);
    __syncthreads();
  }

#pragma unroll
  for (int i = 0; i < 4; ++i)
#pragma unroll
    for (int r = 0; r < 4; ++r) {
      int row = m0 + wm + i * 16 + quad * 4 + r;
#pragma unroll
      for (int j = 0; j < 4; ++j) {
        int col = n0 + wn + j * 16 + l16;
        if constexpr (CF32)
          ((float*)Cv)[(size_t)row * N + col] = acc[i][j][r];
        else
          ((uint16_t*)Cv)[(size_t)row * N + col] = f2bf(acc[i][j][r]);
      }
    }
}

template <bool CF32>
__global__ __launch_bounds__(256) void gemm_fast(const uint16_t* __restrict__ A,
                                                 const uint16_t* __restrict__ B,
                                                 void* __restrict__ Cv,
                                                 int N, int K) {
  __shared__ __align__(16) uint16_t As[128 * 32];
  __shared__ __align__(16) uint16_t Bs[128 * 32];
  gemm_core<CF32>(A, B, Cv, N, K, blockIdx.y * 128, blockIdx.x * 128, As, Bs);
}

// ---------------------------------------------------------------------------
// Fallback GEMM (f32 operands staged+converted in VALU).
// ---------------------------------------------------------------------------
template <bool F32>
__device__ __forceinline__ void load8(const void* __restrict__ base, size_t off,
                                      uint16_t* __restrict__ lds) {
  if constexpr (F32) {
    const float* p = (const float*)base + off;
    float4 a = *(const float4*)p;
    float4 b = *(const float4*)(p + 4);
    uint16_t t[8];
    t[0] = f2bf(a.x); t[1] = f2bf(a.y); t[2] = f2bf(a.z); t[3] = f2bf(a.w);
    t[4] = f2bf(b.x); t[5] = f2bf(b.y); t[6] = f2bf(b.z); t[7] = f2bf(b.w);
    *(float4*)lds = *(float4*)t;
  } else {
    *(float4*)lds = *(const float4*)((const uint16_t*)base + off);
  }
}

template <bool AF32, bool BF32, bool CF32>
__global__ __launch_bounds__(256) void gemm_bt(const void* __restrict__ Av,
                                               const void* __restrict__ Bv,
                                               void* __restrict__ Cv,
                                               int M, int N, int K) {
  __shared__ __align__(16) uint16_t As[128 * 32];
  __shared__ __align__(16) uint16_t Bs[128 * 32];
  const int tid = threadIdx.x;
  const int wave = tid >> 6, lane = tid & 63;
  const int quad = lane >> 4, l16 = lane & 15;
  const int m0 = blockIdx.y * 128, n0 = blockIdx.x * 128;
  const int wm = (wave >> 1) * 64, wn = (wave & 1) * 64;

  floatx4 acc[4][4] = {};

  for (int kb = 0; kb < K; kb += 32) {
    int s = tid;
#pragma unroll
    for (int i = 0; i < 2; ++i, s += 256) {
      int row = s >> 2, cs = (s & 3) * 8;
      load8<AF32>(Av, (size_t)(m0 + row) * K + kb + cs, &As[row * 32 + cs]);
      load8<BF32>(Bv, (size_t)(n0 + row) * K + kb + cs, &Bs[row * 32 + cs]);
    }
    __syncthreads();

    short8 a[4], b[4];
#pragma unroll
    for (int i = 0; i < 4; ++i)
      a[i] = *(const short8*)(&As[(wm + i * 16 + l16) * 32 + quad * 8]);
#pragma unroll
    for (int j = 0; j < 4; ++j)
      b[j] = *(const short8*)(&Bs[(wn + j * 16 + l16) * 32 + quad * 8]);
#pragma unroll
    for (int i = 0; i < 4; ++i)
#pragma unroll
      for (int j = 0; j < 4; ++j)
        acc[i][j] = __builtin_amdgcn_mfma_f32_16x16x32_bf16(a[i], b[j], acc[i][j], 0, 0, 0);
    __syncthreads();
  }

#pragma unroll
  for (int i = 0; i < 4; ++i)
#pragma unroll
    for (int r = 0; r < 4; ++r) {
      int row = m0 + wm + i * 16 + quad * 4 + r;
#pragma unroll
      for (int j = 0; j < 4; ++j) {
        int col = n0 + wn + j * 16 + l16;
        if constexpr (CF32)
          ((float*)Cv)[(size_t)row * N + col] = acc[i][j][r];
        else
          ((uint16_t*)Cv)[(size_t)row * N + col] = f2bf(acc[i][j][r]);
      }
    }
}

// ---------------------------------------------------------------------------
// RoPE in-place on (B*N, H, 128) bf16. cos/sin f32 (N, 64). `scale` folds the
// attention softmax scale into Q for free.
// ---------------------------------------------------------------------------
__global__ void rope_kernel(uint16_t* __restrict__ qk,
                            const float* __restrict__ cosb,
                            const float* __restrict__ sinb, int H, int total,
                            float scale) {
  int idx = blockIdx.x * blockDim.x + threadIdx.x;
  if (idx >= total) return;
  int p = idx & 63;
  int nh = idx >> 6;
  int bn = nh / H;
  int n = bn & (NN - 1);
  size_t base = (size_t)nh * 128 + p * 2;
  uint32_t pr = *(const uint32_t*)(&qk[base]);
  float x0 = bf2f((uint16_t)(pr & 0xffff));
  float x1 = bf2f((uint16_t)(pr >> 16));
  float c = cosb[n * 64 + p];
  float s = sinb[n * 64 + p];
  float o0 = (x0 * c - x1 * s) * scale;
  float o1 = (x0 * s + x1 * c) * scale;
  *(uint32_t*)(&qk[base]) = (uint32_t)f2bf(o0) | ((uint32_t)f2bf(o1) << 16);
}

// ---------------------------------------------------------------------------
// OLD flash attention (4-wave, 16x16, P via LDS) — fallback path only.
// ---------------------------------------------------------------------------
#define KSTR 136
#define VSTR 72
#define PSTR 72

__global__ __launch_bounds__(256, 2) void flash_attn(const uint16_t* __restrict__ Q,
                                                     const uint16_t* __restrict__ K,
                                                     const uint16_t* __restrict__ V,
                                                     uint16_t* __restrict__ O) {
  __shared__ __align__(16) uint16_t Ks[64 * KSTR];
  __shared__ __align__(16) uint16_t Vt[128 * VSTR];
  __shared__ __align__(16) uint16_t Ps[4][32 * PSTR];

  const int tid = threadIdx.x;
  const int wave = tid >> 6, lane = tid & 63;
  const int quad = lane >> 4, l16 = lane & 15;
  const int b = blockIdx.z, h = blockIdx.y, kvh = h >> 2;
  const int qt = gridDim.x - 1 - blockIdx.x;
  const int qlo = qt * 128 + wave * 32;

  short8 aq[2][4];
#pragma unroll
  for (int mi = 0; mi < 2; ++mi) {
    const uint16_t* qrow = Q + (((size_t)(b * NN + qlo + mi * 16 + l16)) * NH + h) * HD;
#pragma unroll
    for (int kd = 0; kd < 4; ++kd)
      aq[mi][kd] = *(const short8*)(&qrow[kd * 32 + quad * 8]);
  }

  float mr[2][4], lr[2][4];
  floatx4 accO[2][8] = {};
#pragma unroll
  for (int mi = 0; mi < 2; ++mi)
#pragma unroll
    for (int r = 0; r < 4; ++r) { mr[mi][r] = -1e30f; lr[mi][r] = 0.f; }

  const float sc2 = 0.08838834764831845f * 1.4426950408889634f;
  const int ntiles = 2 * qt + 2;

  const int srow = tid >> 4;
  const int sl16 = tid & 15;
  const int d8 = sl16 * 8;

  for (int t = 0; t < ntiles; ++t) {
    const int kv0 = t * 64;

#pragma unroll
    for (int i = 0; i < 4; ++i) {
      int row = srow + i * 16;
      size_t gb = (((size_t)(b * NN + kv0 + row)) * NKV + kvh) * HD + d8;
      *(float4*)(&Ks[row * KSTR + d8]) = *(const float4*)(&K[gb]);
      uint16_t vv[8];
      *(float4*)vv = *(const float4*)(&V[gb]);
      int kvp = row ^ ((sl16 & 7) << 3);
#pragma unroll
      for (int j = 0; j < 8; ++j) Vt[(d8 + j) * VSTR + kvp] = vv[j];
    }
    __syncthreads();

    if (kv0 <= qlo + 31) {
      floatx4 s[2][4] = {};
#pragma unroll
      for (int jn = 0; jn < 4; ++jn)
#pragma unroll
        for (int kd = 0; kd < 4; ++kd) {
          short8 bk = *(const short8*)(&Ks[(jn * 16 + l16) * KSTR + kd * 32 + quad * 8]);
          s[0][jn] = __builtin_amdgcn_mfma_f32_16x16x32_bf16(aq[0][kd], bk, s[0][jn], 0, 0, 0);
          s[1][jn] = __builtin_amdgcn_mfma_f32_16x16x32_bf16(aq[1][kd], bk, s[1][jn], 0, 0, 0);
        }

      const bool needmask = (kv0 + 63) > qlo;
#pragma unroll
      for (int mi = 0; mi < 2; ++mi)
#pragma unroll
        for (int jn = 0; jn < 4; ++jn)
#pragma unroll
          for (int r = 0; r < 4; ++r) {
            float v = s[mi][jn][r] * sc2;
            if (needmask) {
              int qr = qlo + mi * 16 + quad * 4 + r;
              int kc = kv0 + jn * 16 + l16;
              if (kc > qr) v = -1e30f;
            }
            s[mi][jn][r] = v;
          }

#pragma unroll
      for (int mi = 0; mi < 2; ++mi)
#pragma unroll
        for (int r = 0; r < 4; ++r) {
          float mx = fmaxf(fmaxf(s[mi][0][r], s[mi][1][r]), fmaxf(s[mi][2][r], s[mi][3][r]));
#pragma unroll
          for (int off = 1; off < 16; off <<= 1)
            mx = fmaxf(mx, __shfl_xor(mx, off, 64));
          float mn = fmaxf(mr[mi][r], mx);
          float al = exp2f(mr[mi][r] - mn);
          mr[mi][r] = mn;
          float rs = 0.f;
#pragma unroll
          for (int jn = 0; jn < 4; ++jn) {
            float p = exp2f(s[mi][jn][r] - mn);
            s[mi][jn][r] = p;
            rs += p;
          }
#pragma unroll
          for (int off = 1; off < 16; off <<= 1)
            rs += __shfl_xor(rs, off, 64);
          lr[mi][r] = lr[mi][r] * al + rs;
#pragma unroll
          for (int jn = 0; jn < 4; ++jn)
            Ps[wave][(mi * 16 + quad * 4 + r) * PSTR + jn * 16 + l16] = f2bf(s[mi][jn][r]);
#pragma unroll
          for (int dt = 0; dt < 8; ++dt) accO[mi][dt][r] *= al;
        }

      short8 ap[2][2];
#pragma unroll
      for (int mi = 0; mi < 2; ++mi)
#pragma unroll
        for (int kk = 0; kk < 2; ++kk)
          ap[mi][kk] = *(const short8*)(&Ps[wave][(mi * 16 + l16) * PSTR + kk * 32 + quad * 8]);
#pragma unroll
      for (int dt = 0; dt < 8; ++dt) {
        int x = (2 * dt + (l16 >> 3)) & 7;
#pragma unroll
        for (int kk = 0; kk < 2; ++kk) {
          int kvb = (kk * 32 + quad * 8) ^ (x << 3);
          short8 bv = *(const short8*)(&Vt[(dt * 16 + l16) * VSTR + kvb]);
          accO[0][dt] = __builtin_amdgcn_mfma_f32_16x16x32_bf16(ap[0][kk], bv, accO[0][dt], 0, 0, 0);
          accO[1][dt] = __builtin_amdgcn_mfma_f32_16x16x32_bf16(ap[1][kk], bv, accO[1][dt], 0, 0, 0);
        }
      }
    }
    __syncthreads();
  }

#pragma unroll
  for (int mi = 0; mi < 2; ++mi)
#pragma unroll
    for (int r = 0; r < 4; ++r) lr[mi][r] = 1.f / lr[mi][r];
#pragma unroll
  for (int mi = 0; mi < 2; ++mi)
#pragma unroll
    for (int dt = 0; dt < 8; ++dt)
#pragma unroll
      for (int r = 0; r < 4; ++r) {
        int qr = qlo + mi * 16 + quad * 4 + r;
        size_t oidx = (((size_t)(b * NN + qr)) * NH + h) * HD + dt * 16 + l16;
        O[oidx] = f2bf(accO[mi][dt][r] * lr[mi][r]);
      }
}

// ---------------------------------------------------------------------------
// NEW flash attention: 8 waves x 32 q-rows, KV tile 64, swapped-operand
// 32x32x16 MFMA (S^T = mfma(K,Q)), V pre-transposed. LDS (64KB, dbuf):
//   K: [64 kv][256B] rows, XOR-swz (row&15)<<4  -> 2-way (free) ds_read
//   V: 64 super-rows x 256B; sr holds d and d+64 halves; off =
//      ((d>>6)*128 + cb) ^ ((sr&15)<<4)        -> 2-way (free) ds_read
// P pack: v_cvt_pk_bf16_f32 + v_permlane32_swap_b32 (T12).
// XCD-clustered 1D grid: each XCD owns 2 (b,kvh) groups (K/V L2-resident).
// ---------------------------------------------------------------------------
__global__ __launch_bounds__(512, 2) void flash_attn2(const uint16_t* __restrict__ Qb,
                                                      const uint16_t* __restrict__ Kb,
                                                      const uint16_t* __restrict__ VTb,
                                                      uint16_t* __restrict__ Ob) {
  __shared__ __align__(16) uint16_t lds[32768];  // 64KB: 2 x (16KB K + 16KB V)

  const int tid = threadIdx.x;
  const int wave = tid >> 6, lane = tid & 63;
  const int l31 = lane & 31, hi = lane >> 5;

  // XCD-clustered decode: 512 blocks; XCD x gets groups {x, x+8} (g = b*8+kvh)
  const int X = blockIdx.x;
  const int slot = X >> 3;
  const int g = (X & 7) + ((slot >> 5) << 3);
  const int w = slot & 31;
  const int b = g >> 3, kvh = g & 7;
  const int h = kvh * 4 + (w >> 3);
  const int qt = 7 - (w & 7);

  const int qbase = qt * 256 + wave * 32;
  const int q_abs = qbase + l31;

  // Q fragments: B-operand rows = q (lane&31), k = d = kb*16 + hi*8 + j
  short8 qf[8];
  {
    const uint16_t* qrow = Qb + (((size_t)(b * NN + q_abs)) * NH + h) * HD;
#pragma unroll
    for (int kb = 0; kb < 8; ++kb)
      qf[kb] = *(const short8*)(qrow + kb * 16 + hi * 8);
  }

  floatx16 accO[4] = {};           // O^T: d = 32j + pat(reg,hi), q = l31
  float mrow = -1e30f, lrow = 0.f;
  const int ntiles = 4 * qt + 4;

  // staging pointers (per-thread, advanced per tile)
  const int toff = (tid & 15) * 16;
  const int r16 = tid >> 4;                  // 0..31
  const int sswz = (r16 & 15) << 4;
  const char* gk = (const char*)Kb +
      (((size_t)(b * NN) + r16) * NKV + kvh) * HD * 2 + (toff ^ sswz);
  const int vu = toff ^ sswz;
  const int vd = r16 + ((vu >> 7) << 6);     // d row for this thread (p=0)
  const char* gv = (const char*)VTb +
      ((size_t)(kvh * 128 + vd)) * (BB * NN) * 2 + (size_t)(b * NN) * 2 + (vu & 127);

#define STAGE(BUF)                                                              \
  {                                                                             \
    char* lb = (char*)lds + (BUF) * 32768;                                      \
    gl2lds16((const uint16_t*)gk, (uint16_t*)(lb + tid * 16));                  \
    gl2lds16((const uint16_t*)(gk + 65536), (uint16_t*)(lb + 8192 + tid * 16)); \
    gl2lds16((const uint16_t*)gv, (uint16_t*)(lb + 16384 + tid * 16));          \
    gl2lds16((const uint16_t*)(gv + 262144),                                    \
             (uint16_t*)(lb + 24576 + tid * 16));                               \
    gk += 131072;                                                               \
    gv += 128;                                                                  \
  }

  STAGE(0);
  __syncthreads();

  for (int t = 0; t < ntiles; ++t) {
    const int buf = t & 1;
    if (t + 1 < ntiles) STAGE(buf ^ 1);  // async prefetch over compute

    if (t * 64 <= qbase + 31) {  // wave-uniform: tile not fully masked
      const int kv0 = t * 64;
      const char* Ksb = (const char*)lds + buf * 32768;
      const char* Vsb = Ksb + 16384;
      const int kswz = (l31 & 15) << 4;

      // S^T = mfma(K, Q): rows m = kv (A=K), cols n = q (B=Q)
      floatx16 s0 = {}, s1 = {};
      __builtin_amdgcn_s_setprio(1);
#pragma unroll
      for (int kb = 0; kb < 8; ++kb) {
        int colB = (kb * 32 + hi * 16) ^ kswz;
        short8 a0 = *(const short8*)(Ksb + l31 * 256 + colB);
        short8 a1 = *(const short8*)(Ksb + 8192 + l31 * 256 + colB);
        s0 = __builtin_amdgcn_mfma_f32_32x32x16_bf16(a0, qf[kb], s0, 0, 0, 0);
        s1 = __builtin_amdgcn_mfma_f32_32x32x16_bf16(a1, qf[kb], s1, 0, 0, 0);
      }
      __builtin_amdgcn_s_setprio(0);

      // causal mask: kv = kv0 + 32c + (r&3)+8*(r>>2)+4hi ; q = q_abs
      if (kv0 + 63 > qbase) {
#pragma unroll
        for (int r = 0; r < 16; ++r) {
          int kvl = kv0 + (r & 3) + 8 * (r >> 2) + 4 * hi;
          if (kvl > q_abs) s0[r] = -1e30f;
          if (kvl + 32 > q_abs) s1[r] = -1e30f;
        }
      }

      // tree max over 32 values + exchange with lane^32
      float mx[8];
#pragma unroll
      for (int i = 0; i < 8; ++i)
        mx[i] = fmaxf(fmaxf(s0[i], s0[i + 8]), fmaxf(s1[i], s1[i + 8]));
#pragma unroll
      for (int st = 4; st > 0; st >>= 1)
#pragma unroll
        for (int i = 0; i < st; ++i) mx[i] = fmaxf(mx[i], mx[i + st]);
      float pm = fmaxf(mx[0], __shfl_xor(mx[0], 32, 64));

      // defer-max (T13)
      if (!__all(pm - mrow <= 8.f)) {
        float mn = fmaxf(mrow, pm);
        float al = exp2f(mrow - mn);
        mrow = mn;
        lrow *= al;
#pragma unroll
        for (int j = 0; j < 4; ++j)
#pragma unroll
          for (int r = 0; r < 16; ++r) accO[j][r] *= al;
      }

#pragma unroll
      for (int r = 0; r < 16; ++r) s0[r] = exp2f(s0[r] - mrow);
#pragma unroll
      for (int r = 0; r < 16; ++r) s1[r] = exp2f(s1[r] - mrow);
      float sm[8];
#pragma unroll
      for (int i = 0; i < 8; ++i)
        sm[i] = (s0[i] + s0[i + 8]) + (s1[i] + s1[i + 8]);
#pragma unroll
      for (int st = 4; st > 0; st >>= 1)
#pragma unroll
        for (int i = 0; i < st; ++i) sm[i] += sm[i + st];
      lrow += sm[0] + __shfl_xor(sm[0], 32, 64);

      // pack P (v_cvt_pk_bf16_f32): W[2j],W[2j+1] = kv [8j+4hi, 8j+4hi+4)
      uint32_t W[16];
#pragma unroll
      for (int i = 0; i < 8; ++i) {
        asm("v_cvt_pk_bf16_f32 %0, %1, %2" : "=v"(W[i]) : "v"(s0[2 * i]), "v"(s0[2 * i + 1]));
        asm("v_cvt_pk_bf16_f32 %0, %1, %2" : "=v"(W[8 + i]) : "v"(s1[2 * i]), "v"(s1[2 * i + 1]));
      }

      // O^T += mfma(V^T, P): B-frags via permlane32_swap half-exchange
      __builtin_amdgcn_s_setprio(1);
#pragma unroll
      for (int g16 = 0; g16 < 4; ++g16) {
        const int base = (g16 >> 1) * 8 + (g16 & 1) * 4;
        uint32_t pa0 = W[base], pb0 = W[base + 2];
        uint32_t pa1 = W[base + 1], pb1 = W[base + 3];
        asm volatile("v_permlane32_swap_b32 %0, %1" : "+v"(pa0), "+v"(pb0));
        asm volatile("v_permlane32_swap_b32 %0, %1" : "+v"(pa1), "+v"(pb1));
        union { uint32_t u[4]; short8 v; } fr;
        fr.u[0] = pa0; fr.u[1] = pa1; fr.u[2] = pb0; fr.u[3] = pb1;
        short8 pb = fr.v;
        const int cb = 32 * g16 + 16 * hi;
#pragma unroll
        for (int j = 0; j < 4; ++j) {
          const int sr = 32 * (j & 1) + l31;
          short8 av = *(const short8*)(Vsb + sr * 256 +
                                       (((j >> 1) * 128 + cb) ^ kswz));
          accO[j] = __builtin_amdgcn_mfma_f32_32x32x16_bf16(av, pb, accO[j], 0, 0, 0);
        }
      }
      __builtin_amdgcn_s_setprio(0);
    }
    __syncthreads();  // drains prefetch (vmcnt0) + guards buffer reuse
  }

  // epilogue: normalize, transpose O^T -> O via per-wave LDS region, store
  float inv = 1.f / lrow;
  uint16_t* ow = &lds[wave * 4096];  // 8KB/wave: [32 q][128 d], swz (q&7)<<4
#pragma unroll
  for (int j = 0; j < 4; ++j)
#pragma unroll
    for (int p = 0; p < 8; ++p) {
      int dd = 32 * j + ((2 * p) & 3) + 8 * (p >> 1) + 4 * hi;
      uint32_t wv = (uint32_t)f2bf(accO[j][2 * p] * inv) |
                    ((uint32_t)f2bf(accO[j][2 * p + 1] * inv) << 16);
      *(uint32_t*)((char*)ow + l31 * 256 + ((dd * 2) ^ ((l31 & 7) << 4))) = wv;
    }
#pragma unroll
  for (int it = 0; it < 8; ++it) {
    int q = it * 4 + (lane >> 4);
    int colB = ((lane & 15) * 16) ^ ((q & 7) << 4);
    short8 v = *(const short8*)((const char*)ow + q * 256 + colB);
    int orow = qt * 256 + wave * 32 + q;
    *(short8*)(Ob + (((size_t)(b * NN + orow)) * NH + h) * HD + (lane & 15) * 8) = v;
  }
#undef STAGE
}

// ---------------------------------------------------------------------------
extern "C" void kernel_launch(void* const* d_in, const int* in_sizes, int n_in,
                              void* d_out, int out_size, void* d_ws, size_t ws_size,
                              hipStream_t stream) {
  const float* x    = (const float*)d_in[0];
  const float* wq   = (const float*)d_in[1];
  const float* wk   = (const float*)d_in[2];
  const float* wv   = (const float*)d_in[3];
  const float* wo   = (const float*)d_in[4];
  const float* cosb = (const float*)d_in[5];
  const float* sinb = (const float*)d_in[6];
  float* out = (float*)d_out;

  const size_t M = (size_t)BB * NN;        // 4096
  const size_t SZ_Q = M * DIM;
  const size_t SZ_W = (size_t)DIM * DIM;
  const size_t SZ_KV = M * NKV * HD;
  const size_t SZ_WKV = (size_t)NKV * HD * DIM;

  const float ATT_SCALE = 0.08838834764831845f * 1.4426950408889634f;

  dim3 blk(256);
  const size_t need_fast =
      2 * (SZ_Q + 3 * SZ_W + 2 * SZ_WKV + 2 * SZ_KV + SZ_Q); // ~201 MB

  // one-time: request 128 KiB dynamic LDS for the 256^2 8-phase GEMMs
  static int g_dyn_ok = -1;
  if (g_dyn_ok < 0) {
    hipError_t e1 = hipFuncSetAttribute(
        reinterpret_cast<const void*>(&gemm256_k<false>),
        hipFuncAttributeMaxDynamicSharedMemorySize, 131072);
    hipError_t e2 = hipFuncSetAttribute(
        reinterpret_cast<const void*>(&gemm256_k<true>),
        hipFuncAttributeMaxDynamicSharedMemorySize, 131072);
    hipError_t e3 = hipFuncSetAttribute(
        reinterpret_cast<const void*>(&gemm_kv256),
        hipFuncAttributeMaxDynamicSharedMemorySize, 131072);
    g_dyn_ok = (e1 == hipSuccess && e2 == hipSuccess && e3 == hipSuccess) ? 1 : 0;
  }

  if (ws_size >= need_fast) {
    uint16_t* p = (uint16_t*)d_ws;
    uint16_t* xb    = p; p += SZ_Q;
    uint16_t* wqb   = p; p += SZ_W;
    uint16_t* wob   = p; p += SZ_W;
    uint16_t* wkb   = p; p += SZ_WKV;
    uint16_t* wvb   = p; p += SZ_WKV;
    uint16_t* qbuf  = p; p += SZ_Q;
    uint16_t* kbuf  = p; p += SZ_KV;
    uint16_t* vtbuf = p; p += SZ_KV;
    uint16_t* obuf  = p;

    // f32 -> bf16 conversions
    cvt_bf16<<<(int)(SZ_Q / 4 / 256), blk, 0, stream>>>(x, xb, SZ_Q / 4);
    cvt_bf16<<<(int)(SZ_W / 4 / 256), blk, 0, stream>>>(wq, wqb, SZ_W / 4);
    cvt_bf16<<<(int)(SZ_WKV / 4 / 256), blk, 0, stream>>>(wk, wkb, SZ_WKV / 4);
    cvt_bf16<<<(int)(SZ_WKV / 4 / 256), blk, 0, stream>>>(wv, wvb, SZ_WKV / 4);
    cvt_bf16<<<(int)(SZ_W / 4 / 256), blk, 0, stream>>>(wo, wob, SZ_W / 4);

    // projections
    if (g_dyn_ok) {
      gemm256_k<false><<<dim3(256), dim3(512), 131072, stream>>>(xb, wqb, qbuf, DIM, DIM, 16);
      gemm_kv256<<<dim3(128), dim3(512), 131072, stream>>>(xb, wkb, wvb, kbuf, vtbuf);
    } else {
      gemm_fast<false><<<dim3(DIM / 128, M / 128), blk, 0, stream>>>(xb, wqb, qbuf, DIM, DIM);
      gemm_fast<false><<<dim3((NKV * HD) / 128, M / 128), blk, 0, stream>>>(xb, wkb, kbuf, NKV * HD, DIM);
      gemm_fast<false><<<dim3((int)(M / 128), (NKV * HD) / 128), blk, 0, stream>>>(wvb, xb, vtbuf, (int)M, DIM);
    }

    // RoPE (Q carries softmax scale folded in)
    int totq = (int)(M * NH * 64);
    int totk = (int)(M * NKV * 64);
    rope_kernel<<<(totq + 255) / 256, blk, 0, stream>>>(qbuf, cosb, sinb, NH, totq, ATT_SCALE);
    rope_kernel<<<(totk + 255) / 256, blk, 0, stream>>>(kbuf, cosb, sinb, NKV, totk, 1.0f);

    // attention (8-wave, 256 q rows/block, XCD-clustered 1D grid)
    flash_attn2<<<dim3(512), dim3(512), 0, stream>>>(qbuf, kbuf, vtbuf, obuf);

    // output projection -> f32
    if (g_dyn_ok)
      gemm256_k<true><<<dim3(256), dim3(512), 131072, stream>>>(obuf, wob, out, DIM, DIM, 16);
    else
      gemm_fast<true><<<dim3(DIM / 128, M / 128), blk, 0, stream>>>(obuf, wob, out, DIM, DIM);
  } else {
    // fallback: f32-staging path (needs ~84 MB)
    uint16_t* qbuf = (uint16_t*)d_ws;
    uint16_t* kbuf = qbuf + SZ_Q;
    uint16_t* vbuf = kbuf + SZ_KV;
    uint16_t* obuf = vbuf + SZ_KV;

    gemm_bt<true, true, false><<<dim3(DIM / 128, M / 128), blk, 0, stream>>>(x, wq, qbuf, M, DIM, DIM);
    gemm_bt<true, true, false><<<dim3((NKV * HD) / 128, M / 128), blk, 0, stream>>>(x, wk, kbuf, M, NKV * HD, DIM);
    gemm_bt<true, true, false><<<dim3((NKV * HD) / 128, M / 128), blk, 0, stream>>>(x, wv, vbuf, M, NKV * HD, DIM);

    int totq = (int)(M * NH * 64);
    int totk = (int)(M * NKV * 64);
    rope_kernel<<<(totq + 255) / 256, blk, 0, stream>>>(qbuf, cosb, sinb, NH, totq, 1.0f);
    rope_kernel<<<(totk + 255) / 256, blk, 0, stream>>>(kbuf, cosb, sinb, NKV, totk, 1.0f);

    flash_attn<<<dim3(NN / 128, NH, BB), blk, 0, stream>>>(qbuf, kbuf, vbuf, obuf);

    gemm_bt<false, true, true><<<dim3(DIM / 128, M / 128), blk, 0, stream>>>(obuf, wo, out, M, DIM, DIM);
  }
}